// Round 1
// 1127.822 us; speedup vs baseline: 1.2981x; 1.2981x over previous
//
#include <hip/hip_runtime.h>
#include <hip/hip_bf16.h>

#define NN 50000
#define NE 800000

typedef __hip_bfloat16 bf16;
typedef __attribute__((ext_vector_type(8))) short bf16x8s;   // 8 bf16 = 4 VGPRs
typedef __attribute__((ext_vector_type(4))) float f32x4;

// ---- workspace layout (bytes) ----
#define OFF_E      0L            // e buffer (SORTED edge order) [NE,64] bf16 = 102.4 MB
#define OFF_HP     102400000L    // hp [NN,128] bf16 : cols 0:64 = h, 64:128 = p
#define OFF_HPAGG  115200000L    // hpagg [NN,128] f32 : segsum of hp over in-edges
#define OFF_EAGGA  140800000L    // eaggA [NN,64] f32 (segsum of current e)
#define OFF_EAGGB  153600000L    // eaggB [NN,64] f32
#define OFF_BS     166400000L    // B_s [NN,64] bf16
#define OFF_BR     172800000L    // B_r [NN,64] bf16
#define OFF_WFMT   179200000L    // formatted weights (<= 614400 B)
#define OFF_ROWPTR 179814400L    // (NN+1) int
#define OFF_COLIDX 180014404L    // NE int (sorted j -> original edge id)
#define OFF_SSEND  183214404L    // NE int (send of sorted edge j)
#define OFF_SEG    186414404L    // NE int (rec of sorted edge j)
#define OFF_CNT    189614404L    // NN int (ends as deg)

// ---- formatted-weight element offsets (bf16 elems) ----
#define FW_HE 0
#define FW_EE 8192
#define FW_PE 10240
#define FW_L0 12288
#define LSTR  69632
#define R_HAGG 0        // [hm rows 0:128 ; hm rows 256:320]  K=192  (in: [haggN|paggN|eagg])
#define R_HMR  12288    // hm rows 128:256                    K=128  (in: [h|p])
#define R_HU   20480    // hu [128,64]
#define R_EUS  28672    // eu rows 0:64
#define R_EUR  32768    // eu rows 64:128
#define R_CEU  36864    // [[I],[I],[eu rows 128:192]] K=192
#define R_PAGG 49152    // [pm rows 0:64 ; pm rows 128:192]   K=128  (in: [paggN|eaggB])
#define R_PMR  57344    // pm rows 64:128                     K=64   (in: p)
#define R_PU   61440    // pu [128,64]

#define AGG_STRIDE 72

__device__ __forceinline__ bf16x8s bfrag(const bf16* w, int c, int t, int lane) {
    return *(const bf16x8s*)(w + ((long)(c*4 + t)*64 + lane)*8);
}
__device__ __forceinline__ bf16x8s cvt8(const float* fp) {
    float4 f0 = ((const float4*)fp)[0];
    float4 f1 = ((const float4*)fp)[1];
    bf16 tmp[8];
    tmp[0]=__float2bfloat16(f0.x); tmp[1]=__float2bfloat16(f0.y);
    tmp[2]=__float2bfloat16(f0.z); tmp[3]=__float2bfloat16(f0.w);
    tmp[4]=__float2bfloat16(f1.x); tmp[5]=__float2bfloat16(f1.y);
    tmp[6]=__float2bfloat16(f1.z); tmp[7]=__float2bfloat16(f1.w);
    return *(const bf16x8s*)tmp;
}

// ======================= weight formatting =======================
__global__ __launch_bounds__(256) void wfmt_k(
    const float* __restrict__ he, const float* __restrict__ ee, const float* __restrict__ pe,
    const float* __restrict__ hm, const float* __restrict__ hu, const float* __restrict__ eu,
    const float* __restrict__ pm, const float* __restrict__ pu, bf16* __restrict__ wf)
{
    int s = blockIdx.x;
    const float* src = nullptr; int rowoff = 0, Ksrc = 0, Kpad = 0, mode = 0, split = 0, gap = 0; long doff = 0;
    if      (s == 0) { src = he; Ksrc = 128; Kpad = 128; doff = FW_HE; }
    else if (s == 1) { src = ee; Ksrc = 16;  Kpad = 32;  doff = FW_EE; }
    else if (s == 2) { src = pe; Ksrc = 16;  Kpad = 32;  doff = FW_PE; }
    else {
        int i = (s - 3) / 9, g = (s - 3) % 9;
        long base = FW_L0 + (long)i*LSTR;
        const float* HM = hm + (long)i*320*64;
        const float* HU = hu + (long)i*128*64;
        const float* EU = eu + (long)i*192*64;
        const float* PM = pm + (long)i*192*64;
        const float* PU = pu + (long)i*128*64;
        switch (g) {
          case 0:  src=HM; mode=4; split=128; gap=128; Kpad=192; doff=base+R_HAGG; break;
          case 1:  src=HM; rowoff=128; Ksrc=128; Kpad=128; doff=base+R_HMR;  break;
          case 2:  src=HU; rowoff=0;   Ksrc=128; Kpad=128; doff=base+R_HU;   break;
          case 3:  src=EU; rowoff=0;   Ksrc=64;  Kpad=64;  doff=base+R_EUS;  break;
          case 4:  src=EU; rowoff=64;  Ksrc=64;  Kpad=64;  doff=base+R_EUR;  break;
          case 5:  src=EU; rowoff=128; Kpad=192; mode=3;   doff=base+R_CEU;  break;
          case 6:  src=PM; mode=4; split=64; gap=64; Kpad=128; doff=base+R_PAGG; break;
          case 7:  src=PM; rowoff=64;  Ksrc=64;  Kpad=64;  doff=base+R_PMR;  break;
          default: src=PU; rowoff=0;   Ksrc=128; Kpad=128; doff=base+R_PU;   break;
        }
    }
    int total = Kpad * 64;
    for (int idx = threadIdx.x; idx < total; idx += 256) {
        int j = idx & 7, l = (idx >> 3) & 63, ct = idx >> 9;
        int c = ct >> 2, t = ct & 3;
        int k = c*32 + (l >> 4)*8 + j;
        int n = t*16 + (l & 15);
        float v;
        if (mode == 4)      v = src[(long)(k + (k >= split ? gap : 0))*64 + n];
        else if (mode == 3) v = (k < 64) ? ((k == n) ? 1.f : 0.f)
                              : (k < 128) ? ((k - 64 == n) ? 1.f : 0.f)
                                          : src[(long)(rowoff + k - 128)*64 + n];
        else                v = (k < Ksrc) ? src[(long)(rowoff + k)*64 + n] : 0.f;
        wf[doff + idx] = __float2bfloat16(v);
    }
}

// ======================= CSR build =======================
__global__ __launch_bounds__(256) void hist_k(const int* __restrict__ rec, int* __restrict__ cnt)
{
    int e = blockIdx.x*256 + threadIdx.x;
    if (e < NE) atomicAdd(&cnt[rec[e]], 1);
}

__global__ __launch_bounds__(1024) void scan_k(const int* __restrict__ cnt, int* __restrict__ rowptr)
{
    __shared__ int sdata[1024];
    __shared__ int s_carry;
    int tid = threadIdx.x;
    if (tid == 0) { s_carry = 0; rowptr[0] = 0; }
    __syncthreads();
    for (int base = 0; base < NN; base += 1024) {
        int i = base + tid;
        int v = (i < NN) ? cnt[i] : 0;
        sdata[tid] = v;
        __syncthreads();
        for (int off = 1; off < 1024; off <<= 1) {
            int t = (tid >= off) ? sdata[tid - off] : 0;
            __syncthreads();
            sdata[tid] += t;
            __syncthreads();
        }
        int total = sdata[1023];
        if (i < NN) rowptr[i + 1] = s_carry + sdata[tid];
        __syncthreads();
        if (tid == 0) s_carry += total;
        __syncthreads();
    }
}

__global__ __launch_bounds__(256) void scatter_k(const int* __restrict__ send, const int* __restrict__ rec,
    const int* __restrict__ rowptr, int* __restrict__ cursor,
    int* __restrict__ colidx, int* __restrict__ ssend, int* __restrict__ seg)
{
    int e = blockIdx.x*256 + threadIdx.x;
    if (e < NE) {
        int r = rec[e];
        int pos = atomicAdd(&cursor[r], 1);
        int d = rowptr[r] + pos;
        colidx[d] = e;
        ssend[d] = send[e];
        seg[d] = r;
    }
}

// ======================= gsum: haggN/paggN = segsum of hp[s] ==============
__global__ __launch_bounds__(256) void gsum_k(const bf16* __restrict__ hp,
    const int* __restrict__ ssend, const int* __restrict__ seg, float* __restrict__ hpagg)
{
    __shared__ int s_ids[256];
    __shared__ int s_seg[256];
    int tid = threadIdx.x, lane = tid & 63, wv = tid >> 6;
    int gbase = blockIdx.x*256;
    s_ids[tid] = ssend[gbase + tid];
    s_seg[tid] = seg[gbase + tid];
    __syncthreads();
    int j0 = wv*64;
    float a0 = 0.f, a1 = 0.f;
    int cur = s_seg[j0];
    #pragma unroll 8
    for (int jj = 0; jj < 64; ++jj) {
        int n = s_seg[j0 + jj];
        if (n != cur) {
            atomicAdd(&hpagg[(long)cur*128 + lane*2],     a0);
            atomicAdd(&hpagg[(long)cur*128 + lane*2 + 1], a1);
            a0 = 0.f; a1 = 0.f; cur = n;
        }
        unsigned v = *(const unsigned*)(hp + (long)s_ids[j0 + jj]*128 + lane*2);
        a0 += __uint_as_float(v << 16);
        a1 += __uint_as_float(v & 0xffff0000u);
    }
    atomicAdd(&hpagg[(long)cur*128 + lane*2],     a0);
    atomicAdd(&hpagg[(long)cur*128 + lane*2 + 1], a1);
}

// ======================= e2: e_new = [B_s|B_r|e]@CEU + eu_b; eagg += segsum(e_new)
template <bool WRITE_E>
__global__ __launch_bounds__(256) void e2_k(
    const bf16* __restrict__ Bs, const bf16* __restrict__ Br, bf16* __restrict__ e_buf,
    const int* __restrict__ ssend, const int* __restrict__ seg, const int* __restrict__ rowptr,
    const bf16* __restrict__ wCEU, const float* __restrict__ eu_b, float* __restrict__ eaggf)
{
    __shared__ __align__(16) bf16 sE[128 * AGG_STRIDE];   // 18432 B
    int tid = threadIdx.x, lane = tid & 63, wv = tid >> 6;
    int l15 = lane & 15, q = lane >> 4;
    int row0 = blockIdx.x*128;
    int wbase = row0 + wv*32;

    int erow[2], sidx[2], ridx[2];
    #pragma unroll
    for (int et = 0; et < 2; ++et) {
        int rc = wbase + et*16 + l15;
        erow[et] = rc;
        sidx[et] = ssend[rc];
        ridx[et] = seg[rc];
    }

    f32x4 acc[2][4];
    {
        float bv[4];
        #pragma unroll
        for (int t = 0; t < 4; ++t) bv[t] = eu_b[t*16 + l15];
        #pragma unroll
        for (int et = 0; et < 2; ++et)
            #pragma unroll
            for (int t = 0; t < 4; ++t) {
                acc[et][t][0]=bv[t]; acc[et][t][1]=bv[t]; acc[et][t][2]=bv[t]; acc[et][t][3]=bv[t];
            }
        #pragma unroll
        for (int c = 0; c < 6; ++c) {
            bf16x8s af[2];
            #pragma unroll
            for (int et = 0; et < 2; ++et) {
                if (c < 2)      af[et] = *(const bf16x8s*)(Bs + (long)sidx[et]*64 + c*32 + q*8);
                else if (c < 4) af[et] = *(const bf16x8s*)(Br + (long)ridx[et]*64 + (c-2)*32 + q*8);
                else            af[et] = *(const bf16x8s*)(e_buf + (long)erow[et]*64 + (c-4)*32 + q*8);
            }
            #pragma unroll
            for (int t = 0; t < 4; ++t) {
                bf16x8s bfv = bfrag(wCEU, c, t, lane);
                #pragma unroll
                for (int et = 0; et < 2; ++et)
                    acc[et][t] = __builtin_amdgcn_mfma_f32_16x16x32_bf16(af[et], bfv, acc[et][t], 0, 0, 0);
            }
        }
    }
    // stage e_new
    #pragma unroll
    for (int et = 0; et < 2; ++et)
        #pragma unroll
        for (int r = 0; r < 4; ++r) {
            int lr = wv*32 + et*16 + q*4 + r;
            #pragma unroll
            for (int t = 0; t < 4; ++t)
                sE[lr*AGG_STRIDE + t*16 + l15] = __float2bfloat16(acc[et][t][r]);
        }
    __syncthreads();

    if (WRITE_E) {
        // vectorized LDS -> global copy of e_new
        #pragma unroll
        for (int w = 0; w < 4; ++w) {
            int ch = w*256 + tid;             // 1024 chunks of 8 bf16
            int rr = ch >> 3, cp = ch & 7;
            *(bf16x8s*)(e_buf + (long)(row0 + rr)*64 + cp*8) =
                *(const bf16x8s*)(sE + rr*AGG_STRIDE + cp*8);
        }
    }

    int col = tid & 63, wpart = tid >> 6;
    int n0 = seg[row0], n1 = seg[row0 + 127];
    for (int n = n0 + wpart; n <= n1; n += 4) {
        int beg = rowptr[n], end = rowptr[n + 1];
        if (beg < row0) beg = row0;
        if (end > row0 + 128) end = row0 + 128;
        if (beg < end) {
            float s = 0.f;
            for (int j = beg; j < end; ++j) s += __bfloat162float(sE[(j - row0)*AGG_STRIDE + col]);
            atomicAdd(&eaggf[(long)n*64 + col], s);
        }
    }
}

// ======================= eemb: e0 embed + bootstrap eagg ==============
__global__ __launch_bounds__(256) void eemb_k(
    const float* __restrict__ e_in, const int* __restrict__ gmap,
    const int* __restrict__ seg, const int* __restrict__ rowptr,
    const bf16* __restrict__ wEE, const float* __restrict__ ee_b,
    float* __restrict__ eaggf, bf16* __restrict__ e_buf)
{
    __shared__ __align__(16) bf16 sE[128 * AGG_STRIDE];
    int tid = threadIdx.x, lane = tid & 63, wv = tid >> 6;
    int l15 = lane & 15, q = lane >> 4;
    int row0 = blockIdx.x*128;

    int em[2];
    #pragma unroll
    for (int et = 0; et < 2; ++et) em[et] = gmap[row0 + wv*32 + et*16 + l15];

    f32x4 acc[2][4];
    float bv[4];
    #pragma unroll
    for (int t = 0; t < 4; ++t) bv[t] = ee_b[t*16 + l15];
    #pragma unroll
    for (int et = 0; et < 2; ++et)
        #pragma unroll
        for (int t = 0; t < 4; ++t) {
            acc[et][t][0]=bv[t]; acc[et][t][1]=bv[t]; acc[et][t][2]=bv[t]; acc[et][t][3]=bv[t];
        }
    {
        bf16x8s af[2];
        #pragma unroll
        for (int et = 0; et < 2; ++et) {
            bf16x8s v = {0,0,0,0,0,0,0,0};
            if (q < 2) v = cvt8(e_in + (long)em[et]*16 + q*8);
            af[et] = v;
        }
        #pragma unroll
        for (int t = 0; t < 4; ++t) {
            bf16x8s bfv = bfrag(wEE, 0, t, lane);
            #pragma unroll
            for (int et = 0; et < 2; ++et)
                acc[et][t] = __builtin_amdgcn_mfma_f32_16x16x32_bf16(af[et], bfv, acc[et][t], 0, 0, 0);
        }
    }
    #pragma unroll
    for (int et = 0; et < 2; ++et)
        #pragma unroll
        for (int r = 0; r < 4; ++r) {
            int lr = wv*32 + et*16 + q*4 + r;
            #pragma unroll
            for (int t = 0; t < 4; ++t)
                sE[lr*AGG_STRIDE + t*16 + l15] = __float2bfloat16(acc[et][t][r]);
        }
    __syncthreads();
    #pragma unroll
    for (int w = 0; w < 4; ++w) {
        int ch = w*256 + tid;
        int rr = ch >> 3, cp = ch & 7;
        *(bf16x8s*)(e_buf + (long)(row0 + rr)*64 + cp*8) =
            *(const bf16x8s*)(sE + rr*AGG_STRIDE + cp*8);
    }
    int col = tid & 63, wpart = tid >> 6;
    int n0 = seg[row0], n1 = seg[row0 + 127];
    for (int n = n0 + wpart; n <= n1; n += 4) {
        int beg = rowptr[n], end = rowptr[n + 1];
        if (beg < row0) beg = row0;
        if (end > row0 + 128) end = row0 + 128;
        if (beg < end) {
            float s = 0.f;
            for (int j = beg; j < end; ++j) s += __bfloat162float(sE[(j - row0)*AGG_STRIDE + col]);
            atomicAdd(&eaggf[(long)n*64 + col], s);
        }
    }
}

// ======================= node kernels =======================
__global__ __launch_bounds__(256) void hemb_k(const float* __restrict__ h_in,
    const bf16* __restrict__ wHE, const float* __restrict__ he_b, bf16* __restrict__ hp)
{
    int tid = threadIdx.x, lane = tid & 63, wv = tid >> 6;
    int l15 = lane & 15, q = lane >> 4;
    int row = blockIdx.x*64 + wv*16 + l15;
    int rc = (row < NN) ? row : NN - 1;
    f32x4 acc[4];
    #pragma unroll
    for (int t = 0; t < 4; ++t) { float b = he_b[t*16 + l15]; acc[t][0]=b; acc[t][1]=b; acc[t][2]=b; acc[t][3]=b; }
    #pragma unroll
    for (int c = 0; c < 4; ++c) {
        bf16x8s af = cvt8(h_in + (long)rc*128 + c*32 + q*8);
        #pragma unroll
        for (int t = 0; t < 4; ++t)
            acc[t] = __builtin_amdgcn_mfma_f32_16x16x32_bf16(af, bfrag(wHE, c, t, lane), acc[t], 0, 0, 0);
    }
    #pragma unroll
    for (int r = 0; r < 4; ++r) {
        int ro = blockIdx.x*64 + wv*16 + q*4 + r;
        if (ro < NN)
            #pragma unroll
            for (int t = 0; t < 4; ++t) hp[(long)ro*128 + t*16 + l15] = __float2bfloat16(acc[t][r]);
    }
}

__global__ __launch_bounds__(256) void pemb_k(const float* __restrict__ p_in,
    const bf16* __restrict__ wPE, const float* __restrict__ pe_b, bf16* __restrict__ hp)
{
    int tid = threadIdx.x, lane = tid & 63, wv = tid >> 6;
    int l15 = lane & 15, q = lane >> 4;
    int row = blockIdx.x*64 + wv*16 + l15;
    int rc = (row < NN) ? row : NN - 1;
    f32x4 acc[4];
    #pragma unroll
    for (int t = 0; t < 4; ++t) { float b = pe_b[t*16 + l15]; acc[t][0]=b; acc[t][1]=b; acc[t][2]=b; acc[t][3]=b; }
    {
        bf16x8s af = {0,0,0,0,0,0,0,0};
        if (q < 2) af = cvt8(p_in + (long)rc*16 + q*8);
        #pragma unroll
        for (int t = 0; t < 4; ++t)
            acc[t] = __builtin_amdgcn_mfma_f32_16x16x32_bf16(af, bfrag(wPE, 0, t, lane), acc[t], 0, 0, 0);
    }
    #pragma unroll
    for (int r = 0; r < 4; ++r) {
        int ro = blockIdx.x*64 + wv*16 + q*4 + r;
        if (ro < NN)
            #pragma unroll
            for (int t = 0; t < 4; ++t) hp[(long)ro*128 + 64 + t*16 + l15] = __float2bfloat16(acc[t][r]);
    }
}

// hfuse: agg = [haggN|paggN|eagg]@HAGG + deg*([h|p]@HMR + hm_b);  h_new = [h|agg]@HU + hu_b
__global__ __launch_bounds__(256) void hfuse_k(
    bf16* __restrict__ hp, const float* __restrict__ hpagg, const float* __restrict__ eagg,
    const int* __restrict__ deg,
    const bf16* __restrict__ wAGG, const bf16* __restrict__ wR, const float* __restrict__ mb,
    const bf16* __restrict__ wU, const float* __restrict__ ub, float* __restrict__ out2)
{
    __shared__ __align__(16) bf16 sAgg[64 * AGG_STRIDE];
    int tid = threadIdx.x, lane = tid & 63, wv = tid >> 6;
    int l15 = lane & 15, q = lane >> 4;
    int row = blockIdx.x*64 + wv*16 + l15;
    int rc = (row < NN) ? row : NN - 1;

    f32x4 aA[4], aR[4];
    #pragma unroll
    for (int t = 0; t < 4; ++t) {
        aA[t][0]=0;aA[t][1]=0;aA[t][2]=0;aA[t][3]=0;
        aR[t][0]=0;aR[t][1]=0;aR[t][2]=0;aR[t][3]=0;
    }
    #pragma unroll
    for (int c = 0; c < 6; ++c) {
        bf16x8s af = (c < 4) ? cvt8(hpagg + (long)rc*128 + c*32 + q*8)
                             : cvt8(eagg + (long)rc*64 + (c-4)*32 + q*8);
        #pragma unroll
        for (int t = 0; t < 4; ++t)
            aA[t] = __builtin_amdgcn_mfma_f32_16x16x32_bf16(af, bfrag(wAGG, c, t, lane), aA[t], 0, 0, 0);
    }
    #pragma unroll
    for (int c = 0; c < 4; ++c) {
        bf16x8s af = *(const bf16x8s*)(hp + (long)rc*128 + c*32 + q*8);
        #pragma unroll
        for (int t = 0; t < 4; ++t)
            aR[t] = __builtin_amdgcn_mfma_f32_16x16x32_bf16(af, bfrag(wR, c, t, lane), aR[t], 0, 0, 0);
    }
    float mbv[4];
    #pragma unroll
    for (int t = 0; t < 4; ++t) mbv[t] = mb[t*16 + l15];
    #pragma unroll
    for (int r = 0; r < 4; ++r) {
        int ro = blockIdx.x*64 + wv*16 + q*4 + r;
        float dg = (float)deg[(ro < NN) ? ro : NN - 1];
        #pragma unroll
        for (int t = 0; t < 4; ++t)
            sAgg[(wv*16 + q*4 + r)*AGG_STRIDE + t*16 + l15] =
                __float2bfloat16(aA[t][r] + dg*(aR[t][r] + mbv[t]));
    }
    __syncthreads();
    f32x4 acc[4];
    #pragma unroll
    for (int t = 0; t < 4; ++t) { float b = ub[t*16 + l15]; acc[t][0]=b; acc[t][1]=b; acc[t][2]=b; acc[t][3]=b; }
    #pragma unroll
    for (int c = 0; c < 4; ++c) {
        bf16x8s af = (c < 2) ? *(const bf16x8s*)(hp + (long)rc*128 + c*32 + q*8)
                             : *(const bf16x8s*)(sAgg + (wv*16 + l15)*AGG_STRIDE + (c-2)*32 + q*8);
        #pragma unroll
        for (int t = 0; t < 4; ++t)
            acc[t] = __builtin_amdgcn_mfma_f32_16x16x32_bf16(af, bfrag(wU, c, t, lane), acc[t], 0, 0, 0);
    }
    #pragma unroll
    for (int r = 0; r < 4; ++r) {
        int ro = blockIdx.x*64 + wv*16 + q*4 + r;
        if (ro < NN) {
            #pragma unroll
            for (int t = 0; t < 4; ++t) {
                float fv = acc[t][r];
                hp[(long)ro*128 + t*16 + l15] = __float2bfloat16(fv);
                if (out2) out2[(long)ro*64 + t*16 + l15] = fv;
            }
        }
    }
}

// pfuse: agg = [paggN|eaggB]@PAGG + deg*(p@PMR + pm_b);  p_new = [p|agg]@PU + pu_b
__global__ __launch_bounds__(256) void pfuse_k(
    bf16* __restrict__ hp, const float* __restrict__ hpagg, const float* __restrict__ eagg,
    const int* __restrict__ deg,
    const bf16* __restrict__ wAGG, const bf16* __restrict__ wR, const float* __restrict__ mb,
    const bf16* __restrict__ wU, const float* __restrict__ ub, float* __restrict__ out2)
{
    __shared__ __align__(16) bf16 sAgg[64 * AGG_STRIDE];
    int tid = threadIdx.x, lane = tid & 63, wv = tid >> 6;
    int l15 = lane & 15, q = lane >> 4;
    int row = blockIdx.x*64 + wv*16 + l15;
    int rc = (row < NN) ? row : NN - 1;

    f32x4 aA[4], aR[4];
    #pragma unroll
    for (int t = 0; t < 4; ++t) {
        aA[t][0]=0;aA[t][1]=0;aA[t][2]=0;aA[t][3]=0;
        aR[t][0]=0;aR[t][1]=0;aR[t][2]=0;aR[t][3]=0;
    }
    #pragma unroll
    for (int c = 0; c < 4; ++c) {
        bf16x8s af = (c < 2) ? cvt8(hpagg + (long)rc*128 + 64 + c*32 + q*8)
                             : cvt8(eagg + (long)rc*64 + (c-2)*32 + q*8);
        #pragma unroll
        for (int t = 0; t < 4; ++t)
            aA[t] = __builtin_amdgcn_mfma_f32_16x16x32_bf16(af, bfrag(wAGG, c, t, lane), aA[t], 0, 0, 0);
    }
    #pragma unroll
    for (int c = 0; c < 2; ++c) {
        bf16x8s af = *(const bf16x8s*)(hp + (long)rc*128 + 64 + c*32 + q*8);
        #pragma unroll
        for (int t = 0; t < 4; ++t)
            aR[t] = __builtin_amdgcn_mfma_f32_16x16x32_bf16(af, bfrag(wR, c, t, lane), aR[t], 0, 0, 0);
    }
    float mbv[4];
    #pragma unroll
    for (int t = 0; t < 4; ++t) mbv[t] = mb[t*16 + l15];
    #pragma unroll
    for (int r = 0; r < 4; ++r) {
        int ro = blockIdx.x*64 + wv*16 + q*4 + r;
        float dg = (float)deg[(ro < NN) ? ro : NN - 1];
        #pragma unroll
        for (int t = 0; t < 4; ++t)
            sAgg[(wv*16 + q*4 + r)*AGG_STRIDE + t*16 + l15] =
                __float2bfloat16(aA[t][r] + dg*(aR[t][r] + mbv[t]));
    }
    __syncthreads();
    f32x4 acc[4];
    #pragma unroll
    for (int t = 0; t < 4; ++t) { float b = ub[t*16 + l15]; acc[t][0]=b; acc[t][1]=b; acc[t][2]=b; acc[t][3]=b; }
    #pragma unroll
    for (int c = 0; c < 4; ++c) {
        bf16x8s af = (c < 2) ? *(const bf16x8s*)(hp + (long)rc*128 + 64 + c*32 + q*8)
                             : *(const bf16x8s*)(sAgg + (wv*16 + l15)*AGG_STRIDE + (c-2)*32 + q*8);
        #pragma unroll
        for (int t = 0; t < 4; ++t)
            acc[t] = __builtin_amdgcn_mfma_f32_16x16x32_bf16(af, bfrag(wU, c, t, lane), acc[t], 0, 0, 0);
    }
    #pragma unroll
    for (int r = 0; r < 4; ++r) {
        int ro = blockIdx.x*64 + wv*16 + q*4 + r;
        if (ro < NN) {
            #pragma unroll
            for (int t = 0; t < 4; ++t) {
                float fv = acc[t][r];
                hp[(long)ro*128 + 64 + t*16 + l15] = __float2bfloat16(fv);
                if (out2) out2[(long)ro*64 + t*16 + l15] = fv;
            }
        }
    }
}

// N3: B_s, B_r from h_new (hp cols 0:64), K=64
__global__ __launch_bounds__(256) void n3_k(const bf16* __restrict__ hp,
    const bf16* __restrict__ wEUs, const bf16* __restrict__ wEUr,
    bf16* __restrict__ Bs, bf16* __restrict__ Br)
{
    int tid = threadIdx.x, lane = tid & 63, wv = tid >> 6;
    int l15 = lane & 15, q = lane >> 4;
    int row = blockIdx.x*64 + wv*16 + l15;
    int rc = (row < NN) ? row : NN - 1;
    f32x4 aBs[4], aBr[4];
    #pragma unroll
    for (int t = 0; t < 4; ++t) {
        aBs[t][0]=0;aBs[t][1]=0;aBs[t][2]=0;aBs[t][3]=0;
        aBr[t][0]=0;aBr[t][1]=0;aBr[t][2]=0;aBr[t][3]=0;
    }
    #pragma unroll
    for (int c = 0; c < 2; ++c) {
        bf16x8s af = *(const bf16x8s*)(hp + (long)rc*128 + c*32 + q*8);
        #pragma unroll
        for (int t = 0; t < 4; ++t) {
            aBs[t] = __builtin_amdgcn_mfma_f32_16x16x32_bf16(af, bfrag(wEUs, c, t, lane), aBs[t], 0, 0, 0);
            aBr[t] = __builtin_amdgcn_mfma_f32_16x16x32_bf16(af, bfrag(wEUr, c, t, lane), aBr[t], 0, 0, 0);
        }
    }
    #pragma unroll
    for (int r = 0; r < 4; ++r) {
        int ro = blockIdx.x*64 + wv*16 + q*4 + r;
        if (ro < NN) {
            #pragma unroll
            for (int t = 0; t < 4; ++t) {
                int col = t*16 + l15;
                Bs[(long)ro*64 + col] = __float2bfloat16(aBs[t][r]);
                Br[(long)ro*64 + col] = __float2bfloat16(aBr[t][r]);
            }
        }
    }
}

// ======================= launch =======================
extern "C" void kernel_launch(void* const* d_in, const int* in_sizes, int n_in,
                              void* d_out, int out_size, void* d_ws, size_t ws_size,
                              hipStream_t stream)
{
    (void)in_sizes; (void)n_in; (void)out_size; (void)ws_size;
    const float* h_in = (const float*)d_in[0];
    const float* e_in = (const float*)d_in[1];
    const float* p_in = (const float*)d_in[2];
    const int*  ei   = (const int*)d_in[3];
    const int* send = ei;
    const int* rec  = ei + NE;
    const float* he_W = (const float*)d_in[4];  const float* he_b = (const float*)d_in[5];
    const float* ee_W = (const float*)d_in[6];  const float* ee_b = (const float*)d_in[7];
    const float* pe_W = (const float*)d_in[8];  const float* pe_b = (const float*)d_in[9];
    const float* hm_W = (const float*)d_in[10]; const float* hm_b = (const float*)d_in[11];
    const float* hu_W = (const float*)d_in[12]; const float* hu_b = (const float*)d_in[13];
    const float* eu_W = (const float*)d_in[14]; const float* eu_b = (const float*)d_in[15];
    const float* pm_W = (const float*)d_in[16]; const float* pm_b = (const float*)d_in[17];
    const float* pu_W = (const float*)d_in[18]; const float* pu_b = (const float*)d_in[19];

    char* ws = (char*)d_ws;
    bf16* e_buf  = (bf16*)(ws + OFF_E);
    bf16* hp     = (bf16*)(ws + OFF_HP);
    float* hpagg = (float*)(ws + OFF_HPAGG);
    float* eaggA = (float*)(ws + OFF_EAGGA);
    float* eaggB = (float*)(ws + OFF_EAGGB);
    bf16* Bs     = (bf16*)(ws + OFF_BS);
    bf16* Br     = (bf16*)(ws + OFF_BR);
    bf16* wf     = (bf16*)(ws + OFF_WFMT);
    int* rowptr  = (int*)(ws + OFF_ROWPTR);
    int* colidx  = (int*)(ws + OFF_COLIDX);
    int* ssend   = (int*)(ws + OFF_SSEND);
    int* segarr  = (int*)(ws + OFF_SEG);
    int* cnt     = (int*)(ws + OFF_CNT);
    float* dout  = (float*)d_out;

    const int EB   = NE / 256;          // 3125
    const int EB2  = NE / 128;          // 6250
    const int NB64 = (NN + 63) / 64;    // 782

    // CSR build; cnt ends as deg
    (void)hipMemsetAsync(cnt, 0, NN * sizeof(int), stream);
    hist_k<<<EB, 256, 0, stream>>>(rec, cnt);
    scan_k<<<1, 1024, 0, stream>>>(cnt, rowptr);
    (void)hipMemsetAsync(cnt, 0, NN * sizeof(int), stream);
    scatter_k<<<EB, 256, 0, stream>>>(send, rec, rowptr, cnt, colidx, ssend, segarr);

    wfmt_k<<<39, 256, 0, stream>>>(he_W, ee_W, pe_W, hm_W, hu_W, eu_W, pm_W, pu_W, wf);

    (void)hipMemsetAsync(eaggA, 0, (long)NN*64*sizeof(float), stream);

    // embeddings
    hemb_k<<<NB64, 256, 0, stream>>>(h_in, wf + FW_HE, he_b, hp);
    pemb_k<<<NB64, 256, 0, stream>>>(p_in, wf + FW_PE, pe_b, hp);
    eemb_k<<<EB2, 256, 0, stream>>>(e_in, colidx, segarr, rowptr,
        wf + FW_EE, ee_b, eaggA, e_buf);

    float* eA = eaggA;
    float* eB = eaggB;
    for (int i = 0; i < 4; ++i) {
        long base = FW_L0 + (long)i*LSTR;
        // raw neighbor sums of h,p
        (void)hipMemsetAsync(hpagg, 0, (long)NN*128*sizeof(float), stream);
        gsum_k<<<EB, 256, 0, stream>>>(hp, ssend, segarr, hpagg);
        // h update (agg compose + A_rec + hu, fused)
        hfuse_k<<<NB64, 256, 0, stream>>>(hp, hpagg, eA, cnt,
            wf + base + R_HAGG, wf + base + R_HMR, hm_b + i*64,
            wf + base + R_HU, hu_b + i*64, (i == 3) ? dout : nullptr);
        // B_s, B_r from h_new
        n3_k<<<NB64, 256, 0, stream>>>(hp, wf + base + R_EUS, wf + base + R_EUR, Bs, Br);
        // e update + eagg segsum
        (void)hipMemsetAsync(eB, 0, (long)NN*64*sizeof(float), stream);
        if (i < 3)
            e2_k<true><<<EB2, 256, 0, stream>>>(Bs, Br, e_buf, ssend, segarr, rowptr,
                wf + base + R_CEU, eu_b + i*64, eB);
        else
            e2_k<false><<<EB2, 256, 0, stream>>>(Bs, Br, e_buf, ssend, segarr, rowptr,
                wf + base + R_CEU, eu_b + i*64, eB);
        // p update (agg compose + C_r + pu, fused)
        pfuse_k<<<NB64, 256, 0, stream>>>(hp, hpagg, eB, cnt,
            wf + base + R_PAGG, wf + base + R_PMR, pm_b + i*64,
            wf + base + R_PU, pu_b + i*64, (i == 3) ? dout + (long)NN*64 : nullptr);
        float* tmp = eA; eA = eB; eB = tmp;
    }
}

// Round 2
// 1038.976 us; speedup vs baseline: 1.4091x; 1.0855x over previous
//
#include <hip/hip_runtime.h>
#include <hip/hip_bf16.h>

#define NN 50000
#define NE 800000

typedef __hip_bfloat16 bf16;
typedef __attribute__((ext_vector_type(8))) short bf16x8s;   // 8 bf16 = 4 VGPRs
typedef __attribute__((ext_vector_type(4))) float f32x4;

// ---- workspace layout (bytes) ----
#define OFF_E      0L            // e buffer (SORTED edge order) [NE,64] bf16 = 102.4 MB
#define OFF_HP     102400000L    // hp [NN,128] bf16 : cols 0:64 = h, 64:128 = p
#define OFF_HPAGG  115200000L    // hpagg [NN,128] f32 : segsum of hp over in-edges
#define OFF_EAGGA  140800000L    // eaggA [NN,64] f32 (segsum of current e)
#define OFF_EAGGB  153600000L    // eaggB [NN,64] f32
#define OFF_BS     166400000L    // B_s [NN,64] bf16
#define OFF_BR     172800000L    // B_r [NN,64] bf16
#define OFF_WFMT   179200000L    // formatted weights (<= 614400 B)
#define OFF_ROWPTR 179814400L    // (NN+1) int
#define OFF_COLIDX 180014404L    // NE int (sorted j -> original edge id)
#define OFF_SSEND  183214404L    // NE int (send of sorted edge j)
#define OFF_SEG    186414404L    // NE int (rec of sorted edge j)
#define OFF_CNT    189614404L    // NN int (ends as deg)
#define OFF_BSUM   189814404L    // SCAN_B int block sums

#define SCAN_B 196               // ceil(NN/256)

// ---- formatted-weight element offsets (bf16 elems) ----
#define FW_HE 0
#define FW_EE 8192
#define FW_PE 10240
#define FW_L0 12288
#define LSTR  69632
#define R_HAGG 0        // [hm rows 0:128 ; hm rows 256:320]  K=192  (in: [haggN|paggN|eagg])
#define R_HMR  12288    // hm rows 128:256                    K=128  (in: [h|p])
#define R_HU   20480    // hu [128,64]
#define R_EUS  28672    // eu rows 0:64
#define R_EUR  32768    // eu rows 64:128
#define R_CEU  36864    // [[I],[I],[eu rows 128:192]] K=192
#define R_PAGG 49152    // [pm rows 0:64 ; pm rows 128:192]   K=128  (in: [paggN|eaggB])
#define R_PMR  57344    // pm rows 64:128                     K=64   (in: p)
#define R_PU   61440    // pu [128,64]

#define AGG_STRIDE 72

__device__ __forceinline__ bf16x8s bfrag(const bf16* w, int c, int t, int lane) {
    return *(const bf16x8s*)(w + ((long)(c*4 + t)*64 + lane)*8);
}
__device__ __forceinline__ bf16x8s cvt8(const float* fp) {
    float4 f0 = ((const float4*)fp)[0];
    float4 f1 = ((const float4*)fp)[1];
    bf16 tmp[8];
    tmp[0]=__float2bfloat16(f0.x); tmp[1]=__float2bfloat16(f0.y);
    tmp[2]=__float2bfloat16(f0.z); tmp[3]=__float2bfloat16(f0.w);
    tmp[4]=__float2bfloat16(f1.x); tmp[5]=__float2bfloat16(f1.y);
    tmp[6]=__float2bfloat16(f1.z); tmp[7]=__float2bfloat16(f1.w);
    return *(const bf16x8s*)tmp;
}

// ======================= weight formatting =======================
__global__ __launch_bounds__(256) void wfmt_k(
    const float* __restrict__ he, const float* __restrict__ ee, const float* __restrict__ pe,
    const float* __restrict__ hm, const float* __restrict__ hu, const float* __restrict__ eu,
    const float* __restrict__ pm, const float* __restrict__ pu, bf16* __restrict__ wf)
{
    int s = blockIdx.x;
    const float* src = nullptr; int rowoff = 0, Ksrc = 0, Kpad = 0, mode = 0, split = 0, gap = 0; long doff = 0;
    if      (s == 0) { src = he; Ksrc = 128; Kpad = 128; doff = FW_HE; }
    else if (s == 1) { src = ee; Ksrc = 16;  Kpad = 32;  doff = FW_EE; }
    else if (s == 2) { src = pe; Ksrc = 16;  Kpad = 32;  doff = FW_PE; }
    else {
        int i = (s - 3) / 9, g = (s - 3) % 9;
        long base = FW_L0 + (long)i*LSTR;
        const float* HM = hm + (long)i*320*64;
        const float* HU = hu + (long)i*128*64;
        const float* EU = eu + (long)i*192*64;
        const float* PM = pm + (long)i*192*64;
        const float* PU = pu + (long)i*128*64;
        switch (g) {
          case 0:  src=HM; mode=4; split=128; gap=128; Kpad=192; doff=base+R_HAGG; break;
          case 1:  src=HM; rowoff=128; Ksrc=128; Kpad=128; doff=base+R_HMR;  break;
          case 2:  src=HU; rowoff=0;   Ksrc=128; Kpad=128; doff=base+R_HU;   break;
          case 3:  src=EU; rowoff=0;   Ksrc=64;  Kpad=64;  doff=base+R_EUS;  break;
          case 4:  src=EU; rowoff=64;  Ksrc=64;  Kpad=64;  doff=base+R_EUR;  break;
          case 5:  src=EU; rowoff=128; Kpad=192; mode=3;   doff=base+R_CEU;  break;
          case 6:  src=PM; mode=4; split=64; gap=64; Kpad=128; doff=base+R_PAGG; break;
          case 7:  src=PM; rowoff=64;  Ksrc=64;  Kpad=64;  doff=base+R_PMR;  break;
          default: src=PU; rowoff=0;   Ksrc=128; Kpad=128; doff=base+R_PU;   break;
        }
    }
    int total = Kpad * 64;
    for (int idx = threadIdx.x; idx < total; idx += 256) {
        int j = idx & 7, l = (idx >> 3) & 63, ct = idx >> 9;
        int c = ct >> 2, t = ct & 3;
        int k = c*32 + (l >> 4)*8 + j;
        int n = t*16 + (l & 15);
        float v;
        if (mode == 4)      v = src[(long)(k + (k >= split ? gap : 0))*64 + n];
        else if (mode == 3) v = (k < 64) ? ((k == n) ? 1.f : 0.f)
                              : (k < 128) ? ((k - 64 == n) ? 1.f : 0.f)
                                          : src[(long)(rowoff + k - 128)*64 + n];
        else                v = (k < Ksrc) ? src[(long)(rowoff + k)*64 + n] : 0.f;
        wf[doff + idx] = __float2bfloat16(v);
    }
}

// ======================= CSR build =======================
__global__ __launch_bounds__(256) void hist_k(const int* __restrict__ rec, int* __restrict__ cnt)
{
    int e = blockIdx.x*256 + threadIdx.x;
    if (e < NE) atomicAdd(&cnt[rec[e]], 1);
}

// 3-phase device-wide scan: rowptr[i+1] = inclusive prefix of cnt
__global__ __launch_bounds__(256) void scan1_k(const int* __restrict__ cnt, int* __restrict__ bsum)
{
    __shared__ int sdata[256];
    int tid = threadIdx.x;
    int i = blockIdx.x*256 + tid;
    sdata[tid] = (i < NN) ? cnt[i] : 0;
    __syncthreads();
    #pragma unroll
    for (int off = 128; off > 0; off >>= 1) {
        if (tid < off) sdata[tid] += sdata[tid + off];
        __syncthreads();
    }
    if (tid == 0) bsum[blockIdx.x] = sdata[0];
}

__global__ __launch_bounds__(256) void scan2_k(int* __restrict__ bsum)
{
    __shared__ int sdata[256];
    int tid = threadIdx.x;
    int v = (tid < SCAN_B) ? bsum[tid] : 0;
    sdata[tid] = v;
    __syncthreads();
    #pragma unroll
    for (int off = 1; off < 256; off <<= 1) {
        int t = (tid >= off) ? sdata[tid - off] : 0;
        __syncthreads();
        sdata[tid] += t;
        __syncthreads();
    }
    if (tid < SCAN_B) bsum[tid] = sdata[tid] - v;   // exclusive
}

__global__ __launch_bounds__(256) void scan3_k(const int* __restrict__ cnt,
    const int* __restrict__ bsum, int* __restrict__ rowptr)
{
    __shared__ int sdata[256];
    int tid = threadIdx.x;
    int i = blockIdx.x*256 + tid;
    sdata[tid] = (i < NN) ? cnt[i] : 0;
    __syncthreads();
    #pragma unroll
    for (int off = 1; off < 256; off <<= 1) {
        int t = (tid >= off) ? sdata[tid - off] : 0;
        __syncthreads();
        sdata[tid] += t;
        __syncthreads();
    }
    if (i < NN) rowptr[i + 1] = sdata[tid] + bsum[blockIdx.x];
    if (i == 0) rowptr[0] = 0;
}

__global__ __launch_bounds__(256) void scatter_k(const int* __restrict__ send, const int* __restrict__ rec,
    const int* __restrict__ rowptr, int* __restrict__ cursor,
    int* __restrict__ colidx, int* __restrict__ ssend, int* __restrict__ seg)
{
    int e = blockIdx.x*256 + threadIdx.x;
    if (e < NE) {
        int r = rec[e];
        int pos = atomicAdd(&cursor[r], 1);
        int d = rowptr[r] + pos;
        colidx[d] = e;
        ssend[d] = send[e];
        seg[d] = r;
    }
}

// ======================= gsum: haggN/paggN = segsum of hp[s] ==============
__global__ __launch_bounds__(256) void gsum_k(const bf16* __restrict__ hp,
    const int* __restrict__ ssend, const int* __restrict__ seg, float* __restrict__ hpagg)
{
    __shared__ int s_ids[256];
    __shared__ int s_seg[256];
    int tid = threadIdx.x, lane = tid & 63, wv = tid >> 6;
    int gbase = blockIdx.x*256;
    s_ids[tid] = ssend[gbase + tid];
    s_seg[tid] = seg[gbase + tid];
    __syncthreads();
    int j0 = wv*64;
    float a0 = 0.f, a1 = 0.f;
    int cur = s_seg[j0];
    #pragma unroll 8
    for (int jj = 0; jj < 64; ++jj) {
        int n = s_seg[j0 + jj];
        if (n != cur) {
            atomicAdd(&hpagg[(long)cur*128 + lane*2],     a0);
            atomicAdd(&hpagg[(long)cur*128 + lane*2 + 1], a1);
            a0 = 0.f; a1 = 0.f; cur = n;
        }
        unsigned v = *(const unsigned*)(hp + (long)s_ids[j0 + jj]*128 + lane*2);
        a0 += __uint_as_float(v << 16);
        a1 += __uint_as_float(v & 0xffff0000u);
    }
    atomicAdd(&hpagg[(long)cur*128 + lane*2],     a0);
    atomicAdd(&hpagg[(long)cur*128 + lane*2 + 1], a1);
}

// ======================= e2: e_new = [B_s|B_r|e]@CEU + eu_b; eagg += segsum(e_new)
template <bool WRITE_E>
__global__ __launch_bounds__(256) void e2_k(
    const bf16* __restrict__ Bs, const bf16* __restrict__ Br, bf16* __restrict__ e_buf,
    const int* __restrict__ ssend, const int* __restrict__ seg, const int* __restrict__ rowptr,
    const bf16* __restrict__ wCEU, const float* __restrict__ eu_b, float* __restrict__ eaggf)
{
    __shared__ __align__(16) bf16 sE[128 * AGG_STRIDE];   // 18432 B
    int tid = threadIdx.x, lane = tid & 63, wv = tid >> 6;
    int l15 = lane & 15, q = lane >> 4;
    int row0 = blockIdx.x*128;
    int wbase = row0 + wv*32;

    int erow[2], sidx[2], ridx[2];
    #pragma unroll
    for (int et = 0; et < 2; ++et) {
        int rc = wbase + et*16 + l15;
        erow[et] = rc;
        sidx[et] = ssend[rc];
        ridx[et] = seg[rc];
    }

    f32x4 acc[2][4];
    {
        float bv[4];
        #pragma unroll
        for (int t = 0; t < 4; ++t) bv[t] = eu_b[t*16 + l15];
        #pragma unroll
        for (int et = 0; et < 2; ++et)
            #pragma unroll
            for (int t = 0; t < 4; ++t) {
                acc[et][t][0]=bv[t]; acc[et][t][1]=bv[t]; acc[et][t][2]=bv[t]; acc[et][t][3]=bv[t];
            }
        #pragma unroll
        for (int c = 0; c < 6; ++c) {
            bf16x8s af[2];
            #pragma unroll
            for (int et = 0; et < 2; ++et) {
                if (c < 2)      af[et] = *(const bf16x8s*)(Bs + (long)sidx[et]*64 + c*32 + q*8);
                else if (c < 4) af[et] = *(const bf16x8s*)(Br + (long)ridx[et]*64 + (c-2)*32 + q*8);
                else            af[et] = *(const bf16x8s*)(e_buf + (long)erow[et]*64 + (c-4)*32 + q*8);
            }
            #pragma unroll
            for (int t = 0; t < 4; ++t) {
                bf16x8s bfv = bfrag(wCEU, c, t, lane);
                #pragma unroll
                for (int et = 0; et < 2; ++et)
                    acc[et][t] = __builtin_amdgcn_mfma_f32_16x16x32_bf16(af[et], bfv, acc[et][t], 0, 0, 0);
            }
        }
    }
    // stage e_new
    #pragma unroll
    for (int et = 0; et < 2; ++et)
        #pragma unroll
        for (int r = 0; r < 4; ++r) {
            int lr = wv*32 + et*16 + q*4 + r;
            #pragma unroll
            for (int t = 0; t < 4; ++t)
                sE[lr*AGG_STRIDE + t*16 + l15] = __float2bfloat16(acc[et][t][r]);
        }
    __syncthreads();

    if (WRITE_E) {
        // vectorized LDS -> global copy of e_new
        #pragma unroll
        for (int w = 0; w < 4; ++w) {
            int ch = w*256 + tid;             // 1024 chunks of 8 bf16
            int rr = ch >> 3, cp = ch & 7;
            *(bf16x8s*)(e_buf + (long)(row0 + rr)*64 + cp*8) =
                *(const bf16x8s*)(sE + rr*AGG_STRIDE + cp*8);
        }
    }

    int col = tid & 63, wpart = tid >> 6;
    int n0 = seg[row0], n1 = seg[row0 + 127];
    for (int n = n0 + wpart; n <= n1; n += 4) {
        int beg = rowptr[n], end = rowptr[n + 1];
        if (beg < row0) beg = row0;
        if (end > row0 + 128) end = row0 + 128;
        if (beg < end) {
            float s = 0.f;
            for (int j = beg; j < end; ++j) s += __bfloat162float(sE[(j - row0)*AGG_STRIDE + col]);
            atomicAdd(&eaggf[(long)n*64 + col], s);
        }
    }
}

// ======================= eemb: e0 embed + bootstrap eagg ==============
__global__ __launch_bounds__(256) void eemb_k(
    const float* __restrict__ e_in, const int* __restrict__ gmap,
    const int* __restrict__ seg, const int* __restrict__ rowptr,
    const bf16* __restrict__ wEE, const float* __restrict__ ee_b,
    float* __restrict__ eaggf, bf16* __restrict__ e_buf)
{
    __shared__ __align__(16) bf16 sE[128 * AGG_STRIDE];
    int tid = threadIdx.x, lane = tid & 63, wv = tid >> 6;
    int l15 = lane & 15, q = lane >> 4;
    int row0 = blockIdx.x*128;

    int em[2];
    #pragma unroll
    for (int et = 0; et < 2; ++et) em[et] = gmap[row0 + wv*32 + et*16 + l15];

    f32x4 acc[2][4];
    float bv[4];
    #pragma unroll
    for (int t = 0; t < 4; ++t) bv[t] = ee_b[t*16 + l15];
    #pragma unroll
    for (int et = 0; et < 2; ++et)
        #pragma unroll
        for (int t = 0; t < 4; ++t) {
            acc[et][t][0]=bv[t]; acc[et][t][1]=bv[t]; acc[et][t][2]=bv[t]; acc[et][t][3]=bv[t];
        }
    {
        bf16x8s af[2];
        #pragma unroll
        for (int et = 0; et < 2; ++et) {
            bf16x8s v = {0,0,0,0,0,0,0,0};
            if (q < 2) v = cvt8(e_in + (long)em[et]*16 + q*8);
            af[et] = v;
        }
        #pragma unroll
        for (int t = 0; t < 4; ++t) {
            bf16x8s bfv = bfrag(wEE, 0, t, lane);
            #pragma unroll
            for (int et = 0; et < 2; ++et)
                acc[et][t] = __builtin_amdgcn_mfma_f32_16x16x32_bf16(af[et], bfv, acc[et][t], 0, 0, 0);
        }
    }
    #pragma unroll
    for (int et = 0; et < 2; ++et)
        #pragma unroll
        for (int r = 0; r < 4; ++r) {
            int lr = wv*32 + et*16 + q*4 + r;
            #pragma unroll
            for (int t = 0; t < 4; ++t)
                sE[lr*AGG_STRIDE + t*16 + l15] = __float2bfloat16(acc[et][t][r]);
        }
    __syncthreads();
    #pragma unroll
    for (int w = 0; w < 4; ++w) {
        int ch = w*256 + tid;
        int rr = ch >> 3, cp = ch & 7;
        *(bf16x8s*)(e_buf + (long)(row0 + rr)*64 + cp*8) =
            *(const bf16x8s*)(sE + rr*AGG_STRIDE + cp*8);
    }
    int col = tid & 63, wpart = tid >> 6;
    int n0 = seg[row0], n1 = seg[row0 + 127];
    for (int n = n0 + wpart; n <= n1; n += 4) {
        int beg = rowptr[n], end = rowptr[n + 1];
        if (beg < row0) beg = row0;
        if (end > row0 + 128) end = row0 + 128;
        if (beg < end) {
            float s = 0.f;
            for (int j = beg; j < end; ++j) s += __bfloat162float(sE[(j - row0)*AGG_STRIDE + col]);
            atomicAdd(&eaggf[(long)n*64 + col], s);
        }
    }
}

// ======================= node kernels =======================
__global__ __launch_bounds__(256) void hemb_k(const float* __restrict__ h_in,
    const bf16* __restrict__ wHE, const float* __restrict__ he_b, bf16* __restrict__ hp)
{
    int tid = threadIdx.x, lane = tid & 63, wv = tid >> 6;
    int l15 = lane & 15, q = lane >> 4;
    int row = blockIdx.x*64 + wv*16 + l15;
    int rc = (row < NN) ? row : NN - 1;
    f32x4 acc[4];
    #pragma unroll
    for (int t = 0; t < 4; ++t) { float b = he_b[t*16 + l15]; acc[t][0]=b; acc[t][1]=b; acc[t][2]=b; acc[t][3]=b; }
    #pragma unroll
    for (int c = 0; c < 4; ++c) {
        bf16x8s af = cvt8(h_in + (long)rc*128 + c*32 + q*8);
        #pragma unroll
        for (int t = 0; t < 4; ++t)
            acc[t] = __builtin_amdgcn_mfma_f32_16x16x32_bf16(af, bfrag(wHE, c, t, lane), acc[t], 0, 0, 0);
    }
    #pragma unroll
    for (int r = 0; r < 4; ++r) {
        int ro = blockIdx.x*64 + wv*16 + q*4 + r;
        if (ro < NN)
            #pragma unroll
            for (int t = 0; t < 4; ++t) hp[(long)ro*128 + t*16 + l15] = __float2bfloat16(acc[t][r]);
    }
}

__global__ __launch_bounds__(256) void pemb_k(const float* __restrict__ p_in,
    const bf16* __restrict__ wPE, const float* __restrict__ pe_b, bf16* __restrict__ hp)
{
    int tid = threadIdx.x, lane = tid & 63, wv = tid >> 6;
    int l15 = lane & 15, q = lane >> 4;
    int row = blockIdx.x*64 + wv*16 + l15;
    int rc = (row < NN) ? row : NN - 1;
    f32x4 acc[4];
    #pragma unroll
    for (int t = 0; t < 4; ++t) { float b = pe_b[t*16 + l15]; acc[t][0]=b; acc[t][1]=b; acc[t][2]=b; acc[t][3]=b; }
    {
        bf16x8s af = {0,0,0,0,0,0,0,0};
        if (q < 2) af = cvt8(p_in + (long)rc*16 + q*8);
        #pragma unroll
        for (int t = 0; t < 4; ++t)
            acc[t] = __builtin_amdgcn_mfma_f32_16x16x32_bf16(af, bfrag(wPE, 0, t, lane), acc[t], 0, 0, 0);
    }
    #pragma unroll
    for (int r = 0; r < 4; ++r) {
        int ro = blockIdx.x*64 + wv*16 + q*4 + r;
        if (ro < NN)
            #pragma unroll
            for (int t = 0; t < 4; ++t) hp[(long)ro*128 + 64 + t*16 + l15] = __float2bfloat16(acc[t][r]);
    }
}

// hfuse: agg = [haggN|paggN|eagg]@HAGG + deg*([h|p]@HMR + hm_b);
//        h_new = [h|agg]@HU + hu_b;  Bs = h_new@EUs, Br = h_new@EUr  (n3 fused)
__global__ __launch_bounds__(256) void hfuse_k(
    bf16* __restrict__ hp, const float* __restrict__ hpagg, const float* __restrict__ eagg,
    const int* __restrict__ deg,
    const bf16* __restrict__ wAGG, const bf16* __restrict__ wR, const float* __restrict__ mb,
    const bf16* __restrict__ wU, const float* __restrict__ ub,
    const bf16* __restrict__ wEUs, const bf16* __restrict__ wEUr,
    bf16* __restrict__ Bs, bf16* __restrict__ Br, float* __restrict__ out2)
{
    __shared__ __align__(16) bf16 sAgg[64 * AGG_STRIDE];
    int tid = threadIdx.x, lane = tid & 63, wv = tid >> 6;
    int l15 = lane & 15, q = lane >> 4;
    int row = blockIdx.x*64 + wv*16 + l15;
    int rc = (row < NN) ? row : NN - 1;

    f32x4 aA[4], aR[4];
    #pragma unroll
    for (int t = 0; t < 4; ++t) {
        aA[t][0]=0;aA[t][1]=0;aA[t][2]=0;aA[t][3]=0;
        aR[t][0]=0;aR[t][1]=0;aR[t][2]=0;aR[t][3]=0;
    }
    #pragma unroll
    for (int c = 0; c < 6; ++c) {
        bf16x8s af = (c < 4) ? cvt8(hpagg + (long)rc*128 + c*32 + q*8)
                             : cvt8(eagg + (long)rc*64 + (c-4)*32 + q*8);
        #pragma unroll
        for (int t = 0; t < 4; ++t)
            aA[t] = __builtin_amdgcn_mfma_f32_16x16x32_bf16(af, bfrag(wAGG, c, t, lane), aA[t], 0, 0, 0);
    }
    #pragma unroll
    for (int c = 0; c < 4; ++c) {
        bf16x8s af = *(const bf16x8s*)(hp + (long)rc*128 + c*32 + q*8);
        #pragma unroll
        for (int t = 0; t < 4; ++t)
            aR[t] = __builtin_amdgcn_mfma_f32_16x16x32_bf16(af, bfrag(wR, c, t, lane), aR[t], 0, 0, 0);
    }
    float mbv[4];
    #pragma unroll
    for (int t = 0; t < 4; ++t) mbv[t] = mb[t*16 + l15];
    #pragma unroll
    for (int r = 0; r < 4; ++r) {
        int ro = blockIdx.x*64 + wv*16 + q*4 + r;
        float dg = (float)deg[(ro < NN) ? ro : NN - 1];
        #pragma unroll
        for (int t = 0; t < 4; ++t)
            sAgg[(wv*16 + q*4 + r)*AGG_STRIDE + t*16 + l15] =
                __float2bfloat16(aA[t][r] + dg*(aR[t][r] + mbv[t]));
    }
    __syncthreads();
    f32x4 acc[4];
    #pragma unroll
    for (int t = 0; t < 4; ++t) { float b = ub[t*16 + l15]; acc[t][0]=b; acc[t][1]=b; acc[t][2]=b; acc[t][3]=b; }
    #pragma unroll
    for (int c = 0; c < 4; ++c) {
        bf16x8s af = (c < 2) ? *(const bf16x8s*)(hp + (long)rc*128 + c*32 + q*8)
                             : *(const bf16x8s*)(sAgg + (wv*16 + l15)*AGG_STRIDE + (c-2)*32 + q*8);
        #pragma unroll
        for (int t = 0; t < 4; ++t)
            acc[t] = __builtin_amdgcn_mfma_f32_16x16x32_bf16(af, bfrag(wU, c, t, lane), acc[t], 0, 0, 0);
    }
    __syncthreads();   // sAgg reads for HU done; re-stage h_new
    #pragma unroll
    for (int r = 0; r < 4; ++r) {
        int ro = blockIdx.x*64 + wv*16 + q*4 + r;
        #pragma unroll
        for (int t = 0; t < 4; ++t) {
            float fv = acc[t][r];
            bf16 hv = __float2bfloat16(fv);
            sAgg[(wv*16 + q*4 + r)*AGG_STRIDE + t*16 + l15] = hv;
            if (ro < NN) {
                hp[(long)ro*128 + t*16 + l15] = hv;
                if (out2) out2[(long)ro*64 + t*16 + l15] = fv;
            }
        }
    }
    __syncthreads();
    // fused n3: Bs = h_new @ EUs, Br = h_new @ EUr  (K=64)
    f32x4 aBs[4], aBr[4];
    #pragma unroll
    for (int t = 0; t < 4; ++t) {
        aBs[t][0]=0;aBs[t][1]=0;aBs[t][2]=0;aBs[t][3]=0;
        aBr[t][0]=0;aBr[t][1]=0;aBr[t][2]=0;aBr[t][3]=0;
    }
    #pragma unroll
    for (int c = 0; c < 2; ++c) {
        bf16x8s af = *(const bf16x8s*)(sAgg + (wv*16 + l15)*AGG_STRIDE + c*32 + q*8);
        #pragma unroll
        for (int t = 0; t < 4; ++t) {
            aBs[t] = __builtin_amdgcn_mfma_f32_16x16x32_bf16(af, bfrag(wEUs, c, t, lane), aBs[t], 0, 0, 0);
            aBr[t] = __builtin_amdgcn_mfma_f32_16x16x32_bf16(af, bfrag(wEUr, c, t, lane), aBr[t], 0, 0, 0);
        }
    }
    #pragma unroll
    for (int r = 0; r < 4; ++r) {
        int ro = blockIdx.x*64 + wv*16 + q*4 + r;
        if (ro < NN) {
            #pragma unroll
            for (int t = 0; t < 4; ++t) {
                int col = t*16 + l15;
                Bs[(long)ro*64 + col] = __float2bfloat16(aBs[t][r]);
                Br[(long)ro*64 + col] = __float2bfloat16(aBr[t][r]);
            }
        }
    }
}

// pfuse: agg = [paggN|eaggB]@PAGG + deg*(p@PMR + pm_b);  p_new = [p|agg]@PU + pu_b
__global__ __launch_bounds__(256) void pfuse_k(
    bf16* __restrict__ hp, const float* __restrict__ hpagg, const float* __restrict__ eagg,
    const int* __restrict__ deg,
    const bf16* __restrict__ wAGG, const bf16* __restrict__ wR, const float* __restrict__ mb,
    const bf16* __restrict__ wU, const float* __restrict__ ub, float* __restrict__ out2)
{
    __shared__ __align__(16) bf16 sAgg[64 * AGG_STRIDE];
    int tid = threadIdx.x, lane = tid & 63, wv = tid >> 6;
    int l15 = lane & 15, q = lane >> 4;
    int row = blockIdx.x*64 + wv*16 + l15;
    int rc = (row < NN) ? row : NN - 1;

    f32x4 aA[4], aR[4];
    #pragma unroll
    for (int t = 0; t < 4; ++t) {
        aA[t][0]=0;aA[t][1]=0;aA[t][2]=0;aA[t][3]=0;
        aR[t][0]=0;aR[t][1]=0;aR[t][2]=0;aR[t][3]=0;
    }
    #pragma unroll
    for (int c = 0; c < 4; ++c) {
        bf16x8s af = (c < 2) ? cvt8(hpagg + (long)rc*128 + 64 + c*32 + q*8)
                             : cvt8(eagg + (long)rc*64 + (c-2)*32 + q*8);
        #pragma unroll
        for (int t = 0; t < 4; ++t)
            aA[t] = __builtin_amdgcn_mfma_f32_16x16x32_bf16(af, bfrag(wAGG, c, t, lane), aA[t], 0, 0, 0);
    }
    #pragma unroll
    for (int c = 0; c < 2; ++c) {
        bf16x8s af = *(const bf16x8s*)(hp + (long)rc*128 + 64 + c*32 + q*8);
        #pragma unroll
        for (int t = 0; t < 4; ++t)
            aR[t] = __builtin_amdgcn_mfma_f32_16x16x32_bf16(af, bfrag(wR, c, t, lane), aR[t], 0, 0, 0);
    }
    float mbv[4];
    #pragma unroll
    for (int t = 0; t < 4; ++t) mbv[t] = mb[t*16 + l15];
    #pragma unroll
    for (int r = 0; r < 4; ++r) {
        int ro = blockIdx.x*64 + wv*16 + q*4 + r;
        float dg = (float)deg[(ro < NN) ? ro : NN - 1];
        #pragma unroll
        for (int t = 0; t < 4; ++t)
            sAgg[(wv*16 + q*4 + r)*AGG_STRIDE + t*16 + l15] =
                __float2bfloat16(aA[t][r] + dg*(aR[t][r] + mbv[t]));
    }
    __syncthreads();
    f32x4 acc[4];
    #pragma unroll
    for (int t = 0; t < 4; ++t) { float b = ub[t*16 + l15]; acc[t][0]=b; acc[t][1]=b; acc[t][2]=b; acc[t][3]=b; }
    #pragma unroll
    for (int c = 0; c < 4; ++c) {
        bf16x8s af = (c < 2) ? *(const bf16x8s*)(hp + (long)rc*128 + 64 + c*32 + q*8)
                             : *(const bf16x8s*)(sAgg + (wv*16 + l15)*AGG_STRIDE + (c-2)*32 + q*8);
        #pragma unroll
        for (int t = 0; t < 4; ++t)
            acc[t] = __builtin_amdgcn_mfma_f32_16x16x32_bf16(af, bfrag(wU, c, t, lane), acc[t], 0, 0, 0);
    }
    #pragma unroll
    for (int r = 0; r < 4; ++r) {
        int ro = blockIdx.x*64 + wv*16 + q*4 + r;
        if (ro < NN) {
            #pragma unroll
            for (int t = 0; t < 4; ++t) {
                float fv = acc[t][r];
                hp[(long)ro*128 + 64 + t*16 + l15] = __float2bfloat16(fv);
                if (out2) out2[(long)ro*64 + t*16 + l15] = fv;
            }
        }
    }
}

// ======================= launch =======================
extern "C" void kernel_launch(void* const* d_in, const int* in_sizes, int n_in,
                              void* d_out, int out_size, void* d_ws, size_t ws_size,
                              hipStream_t stream)
{
    (void)in_sizes; (void)n_in; (void)out_size; (void)ws_size;
    const float* h_in = (const float*)d_in[0];
    const float* e_in = (const float*)d_in[1];
    const float* p_in = (const float*)d_in[2];
    const int*  ei   = (const int*)d_in[3];
    const int* send = ei;
    const int* rec  = ei + NE;
    const float* he_W = (const float*)d_in[4];  const float* he_b = (const float*)d_in[5];
    const float* ee_W = (const float*)d_in[6];  const float* ee_b = (const float*)d_in[7];
    const float* pe_W = (const float*)d_in[8];  const float* pe_b = (const float*)d_in[9];
    const float* hm_W = (const float*)d_in[10]; const float* hm_b = (const float*)d_in[11];
    const float* hu_W = (const float*)d_in[12]; const float* hu_b = (const float*)d_in[13];
    const float* eu_W = (const float*)d_in[14]; const float* eu_b = (const float*)d_in[15];
    const float* pm_W = (const float*)d_in[16]; const float* pm_b = (const float*)d_in[17];
    const float* pu_W = (const float*)d_in[18]; const float* pu_b = (const float*)d_in[19];

    char* ws = (char*)d_ws;
    bf16* e_buf  = (bf16*)(ws + OFF_E);
    bf16* hp     = (bf16*)(ws + OFF_HP);
    float* hpagg = (float*)(ws + OFF_HPAGG);
    float* eaggA = (float*)(ws + OFF_EAGGA);
    float* eaggB = (float*)(ws + OFF_EAGGB);
    bf16* Bs     = (bf16*)(ws + OFF_BS);
    bf16* Br     = (bf16*)(ws + OFF_BR);
    bf16* wf     = (bf16*)(ws + OFF_WFMT);
    int* rowptr  = (int*)(ws + OFF_ROWPTR);
    int* colidx  = (int*)(ws + OFF_COLIDX);
    int* ssend   = (int*)(ws + OFF_SSEND);
    int* segarr  = (int*)(ws + OFF_SEG);
    int* cnt     = (int*)(ws + OFF_CNT);
    int* bsum    = (int*)(ws + OFF_BSUM);
    float* dout  = (float*)d_out;

    const int EB   = NE / 256;          // 3125
    const int EB2  = NE / 128;          // 6250
    const int NB64 = (NN + 63) / 64;    // 782

    // CSR build; cnt ends as deg
    (void)hipMemsetAsync(cnt, 0, NN * sizeof(int), stream);
    hist_k<<<EB, 256, 0, stream>>>(rec, cnt);
    scan1_k<<<SCAN_B, 256, 0, stream>>>(cnt, bsum);
    scan2_k<<<1, 256, 0, stream>>>(bsum);
    scan3_k<<<SCAN_B, 256, 0, stream>>>(cnt, bsum, rowptr);
    (void)hipMemsetAsync(cnt, 0, NN * sizeof(int), stream);
    scatter_k<<<EB, 256, 0, stream>>>(send, rec, rowptr, cnt, colidx, ssend, segarr);

    wfmt_k<<<39, 256, 0, stream>>>(he_W, ee_W, pe_W, hm_W, hu_W, eu_W, pm_W, pu_W, wf);

    (void)hipMemsetAsync(eaggA, 0, (long)NN*64*sizeof(float), stream);

    // embeddings
    hemb_k<<<NB64, 256, 0, stream>>>(h_in, wf + FW_HE, he_b, hp);
    pemb_k<<<NB64, 256, 0, stream>>>(p_in, wf + FW_PE, pe_b, hp);
    eemb_k<<<EB2, 256, 0, stream>>>(e_in, colidx, segarr, rowptr,
        wf + FW_EE, ee_b, eaggA, e_buf);

    float* eA = eaggA;
    float* eB = eaggB;
    for (int i = 0; i < 4; ++i) {
        long base = FW_L0 + (long)i*LSTR;
        // raw neighbor sums of h,p
        (void)hipMemsetAsync(hpagg, 0, (long)NN*128*sizeof(float), stream);
        gsum_k<<<EB, 256, 0, stream>>>(hp, ssend, segarr, hpagg);
        // h update (agg compose + A_rec + hu + n3, fused)
        hfuse_k<<<NB64, 256, 0, stream>>>(hp, hpagg, eA, cnt,
            wf + base + R_HAGG, wf + base + R_HMR, hm_b + i*64,
            wf + base + R_HU, hu_b + i*64,
            wf + base + R_EUS, wf + base + R_EUR, Bs, Br,
            (i == 3) ? dout : nullptr);
        // e update + eagg segsum
        (void)hipMemsetAsync(eB, 0, (long)NN*64*sizeof(float), stream);
        if (i < 3)
            e2_k<true><<<EB2, 256, 0, stream>>>(Bs, Br, e_buf, ssend, segarr, rowptr,
                wf + base + R_CEU, eu_b + i*64, eB);
        else
            e2_k<false><<<EB2, 256, 0, stream>>>(Bs, Br, e_buf, ssend, segarr, rowptr,
                wf + base + R_CEU, eu_b + i*64, eB);
        // p update (agg compose + C_r + pu, fused)
        pfuse_k<<<NB64, 256, 0, stream>>>(hp, hpagg, eB, cnt,
            wf + base + R_PAGG, wf + base + R_PMR, pm_b + i*64,
            wf + base + R_PU, pu_b + i*64, (i == 3) ? dout + (long)NN*64 : nullptr);
        float* tmp = eA; eA = eB; eB = tmp;
    }
}

// Round 3
// 1011.312 us; speedup vs baseline: 1.4477x; 1.0274x over previous
//
#include <hip/hip_runtime.h>
#include <hip/hip_bf16.h>

#define NN 50000
#define NE 800000

typedef __hip_bfloat16 bf16;
typedef __attribute__((ext_vector_type(8))) short bf16x8s;   // 8 bf16 = 4 VGPRs
typedef __attribute__((ext_vector_type(4))) float f32x4;

// ---- workspace layout (bytes) ----
#define OFF_E      0L            // e buffer (SORTED edge order) [NE,64] bf16 = 102.4 MB
#define OFF_HP     102400000L    // hp [NN,128] bf16 : cols 0:64 = h, 64:128 = p
#define OFF_HPAGG  115200000L    // hpagg [NN,128] f32 : segsum of hp over in-edges
#define OFF_EAGGA  140800000L    // eaggA [NN,64] f32 (segsum of current e)   (contiguous w/ HPAGG)
#define OFF_EAGGB  153600000L    // eaggB [NN,64] f32                          (contiguous)
#define OFF_BS     166400000L    // B_s [NN,64] bf16
#define OFF_BR     172800000L    // B_r [NN,64] bf16
#define OFF_WFMT   179200000L    // formatted weights (<= 614400 B)
#define OFF_ROWPTR 179814400L    // (NN+1) int
#define OFF_COLIDX 180014404L    // NE int (sorted j -> original edge id)
#define OFF_SSEND  183214404L    // NE int (send of sorted edge j)
#define OFF_SEG    186414404L    // NE int (rec of sorted edge j)
#define OFF_CNT    189614404L    // NN int (ends as deg)
#define OFF_BSUM   189814404L    // SCAN_B int block sums

#define SCAN_B 196               // ceil(NN/256)

// ---- formatted-weight element offsets (bf16 elems) ----
#define FW_HE 0
#define FW_EE 8192
#define FW_PE 10240
#define FW_L0 12288
#define LSTR  69632
#define R_HAGG 0        // [hm rows 0:128 ; hm rows 256:320]  K=192  (in: [haggN|paggN|eagg])
#define R_HMR  12288    // hm rows 128:256                    K=128  (in: [h|p])
#define R_HU   20480    // hu [128,64]
#define R_EUS  28672    // eu rows 0:64
#define R_EUR  32768    // eu rows 64:128
#define R_CEU  36864    // [[I],[I],[eu rows 128:192]] K=192
#define R_PAGG 49152    // [pm rows 0:64 ; pm rows 128:192]   K=128  (in: [paggN|eaggB])
#define R_PMR  57344    // pm rows 64:128                     K=64   (in: p)
#define R_PU   61440    // pu [128,64]

#define AGG_STRIDE 72

__device__ __forceinline__ bf16x8s bfrag(const bf16* w, int c, int t, int lane) {
    return *(const bf16x8s*)(w + ((long)(c*4 + t)*64 + lane)*8);
}
__device__ __forceinline__ bf16x8s cvt8(const float* fp) {
    float4 f0 = ((const float4*)fp)[0];
    float4 f1 = ((const float4*)fp)[1];
    bf16 tmp[8];
    tmp[0]=__float2bfloat16(f0.x); tmp[1]=__float2bfloat16(f0.y);
    tmp[2]=__float2bfloat16(f0.z); tmp[3]=__float2bfloat16(f0.w);
    tmp[4]=__float2bfloat16(f1.x); tmp[5]=__float2bfloat16(f1.y);
    tmp[6]=__float2bfloat16(f1.z); tmp[7]=__float2bfloat16(f1.w);
    return *(const bf16x8s*)tmp;
}

// ======================= weight formatting =======================
__global__ __launch_bounds__(256) void wfmt_k(
    const float* __restrict__ he, const float* __restrict__ ee, const float* __restrict__ pe,
    const float* __restrict__ hm, const float* __restrict__ hu, const float* __restrict__ eu,
    const float* __restrict__ pm, const float* __restrict__ pu, bf16* __restrict__ wf)
{
    int s = blockIdx.x;
    const float* src = nullptr; int rowoff = 0, Ksrc = 0, Kpad = 0, mode = 0, split = 0, gap = 0; long doff = 0;
    if      (s == 0) { src = he; Ksrc = 128; Kpad = 128; doff = FW_HE; }
    else if (s == 1) { src = ee; Ksrc = 16;  Kpad = 32;  doff = FW_EE; }
    else if (s == 2) { src = pe; Ksrc = 16;  Kpad = 32;  doff = FW_PE; }
    else {
        int i = (s - 3) / 9, g = (s - 3) % 9;
        long base = FW_L0 + (long)i*LSTR;
        const float* HM = hm + (long)i*320*64;
        const float* HU = hu + (long)i*128*64;
        const float* EU = eu + (long)i*192*64;
        const float* PM = pm + (long)i*192*64;
        const float* PU = pu + (long)i*128*64;
        switch (g) {
          case 0:  src=HM; mode=4; split=128; gap=128; Kpad=192; doff=base+R_HAGG; break;
          case 1:  src=HM; rowoff=128; Ksrc=128; Kpad=128; doff=base+R_HMR;  break;
          case 2:  src=HU; rowoff=0;   Ksrc=128; Kpad=128; doff=base+R_HU;   break;
          case 3:  src=EU; rowoff=0;   Ksrc=64;  Kpad=64;  doff=base+R_EUS;  break;
          case 4:  src=EU; rowoff=64;  Ksrc=64;  Kpad=64;  doff=base+R_EUR;  break;
          case 5:  src=EU; rowoff=128; Kpad=192; mode=3;   doff=base+R_CEU;  break;
          case 6:  src=PM; mode=4; split=64; gap=64; Kpad=128; doff=base+R_PAGG; break;
          case 7:  src=PM; rowoff=64;  Ksrc=64;  Kpad=64;  doff=base+R_PMR;  break;
          default: src=PU; rowoff=0;   Ksrc=128; Kpad=128; doff=base+R_PU;   break;
        }
    }
    int total = Kpad * 64;
    for (int idx = threadIdx.x; idx < total; idx += 256) {
        int j = idx & 7, l = (idx >> 3) & 63, ct = idx >> 9;
        int c = ct >> 2, t = ct & 3;
        int k = c*32 + (l >> 4)*8 + j;
        int n = t*16 + (l & 15);
        float v;
        if (mode == 4)      v = src[(long)(k + (k >= split ? gap : 0))*64 + n];
        else if (mode == 3) v = (k < 64) ? ((k == n) ? 1.f : 0.f)
                              : (k < 128) ? ((k - 64 == n) ? 1.f : 0.f)
                                          : src[(long)(rowoff + k - 128)*64 + n];
        else                v = (k < Ksrc) ? src[(long)(rowoff + k)*64 + n] : 0.f;
        wf[doff + idx] = __float2bfloat16(v);
    }
}

// ======================= CSR build =======================
__global__ __launch_bounds__(256) void hist_k(const int* __restrict__ rec, int* __restrict__ cnt)
{
    int e = blockIdx.x*256 + threadIdx.x;
    if (e < NE) atomicAdd(&cnt[rec[e]], 1);
}

// 3-phase device-wide scan: rowptr[i+1] = inclusive prefix of cnt
__global__ __launch_bounds__(256) void scan1_k(const int* __restrict__ cnt, int* __restrict__ bsum)
{
    __shared__ int sdata[256];
    int tid = threadIdx.x;
    int i = blockIdx.x*256 + tid;
    sdata[tid] = (i < NN) ? cnt[i] : 0;
    __syncthreads();
    #pragma unroll
    for (int off = 128; off > 0; off >>= 1) {
        if (tid < off) sdata[tid] += sdata[tid + off];
        __syncthreads();
    }
    if (tid == 0) bsum[blockIdx.x] = sdata[0];
}

__global__ __launch_bounds__(256) void scan2_k(int* __restrict__ bsum)
{
    __shared__ int sdata[256];
    int tid = threadIdx.x;
    int v = (tid < SCAN_B) ? bsum[tid] : 0;
    sdata[tid] = v;
    __syncthreads();
    #pragma unroll
    for (int off = 1; off < 256; off <<= 1) {
        int t = (tid >= off) ? sdata[tid - off] : 0;
        __syncthreads();
        sdata[tid] += t;
        __syncthreads();
    }
    if (tid < SCAN_B) bsum[tid] = sdata[tid] - v;   // exclusive
}

__global__ __launch_bounds__(256) void scan3_k(const int* __restrict__ cnt,
    const int* __restrict__ bsum, int* __restrict__ rowptr)
{
    __shared__ int sdata[256];
    int tid = threadIdx.x;
    int i = blockIdx.x*256 + tid;
    sdata[tid] = (i < NN) ? cnt[i] : 0;
    __syncthreads();
    #pragma unroll
    for (int off = 1; off < 256; off <<= 1) {
        int t = (tid >= off) ? sdata[tid - off] : 0;
        __syncthreads();
        sdata[tid] += t;
        __syncthreads();
    }
    if (i < NN) rowptr[i + 1] = sdata[tid] + bsum[blockIdx.x];
    if (i == 0) rowptr[0] = 0;
}

// scatter ONLY colidx (single random-write stream; 3.2 MB working set merges in L2)
__global__ __launch_bounds__(256) void scatter_k(const int* __restrict__ rec,
    const int* __restrict__ rowptr, int* __restrict__ cursor, int* __restrict__ colidx)
{
    int e = blockIdx.x*256 + threadIdx.x;
    if (e < NE) {
        int r = rec[e];
        int pos = atomicAdd(&cursor[r], 1);
        colidx[rowptr[r] + pos] = e;
    }
}

// fillseg: seg[j] via binary search on rowptr (coalesced write);
//          ssend[j] = send[colidx[j]] (gather from L2-resident send, coalesced write)
__global__ __launch_bounds__(256) void fillseg_k(const int* __restrict__ rowptr,
    const int* __restrict__ colidx, const int* __restrict__ send,
    int* __restrict__ seg, int* __restrict__ ssend)
{
    int j = blockIdx.x*256 + threadIdx.x;
    if (j < NE) {
        int lo = 0, hi = NN - 1;
        while (lo < hi) {
            int mid = (lo + hi + 1) >> 1;
            if (rowptr[mid] <= j) lo = mid; else hi = mid - 1;
        }
        seg[j] = lo;
        ssend[j] = send[colidx[j]];
    }
}

// ======================= gsum: haggN/paggN = segsum of hp[s] ==============
__global__ __launch_bounds__(256) void gsum_k(const bf16* __restrict__ hp,
    const int* __restrict__ ssend, const int* __restrict__ seg, float* __restrict__ hpagg)
{
    __shared__ int s_ids[256];
    __shared__ int s_seg[256];
    int tid = threadIdx.x, lane = tid & 63, wv = tid >> 6;
    int gbase = blockIdx.x*256;
    s_ids[tid] = ssend[gbase + tid];
    s_seg[tid] = seg[gbase + tid];
    __syncthreads();
    int j0 = wv*64;
    float a0 = 0.f, a1 = 0.f;
    int cur = s_seg[j0];
    #pragma unroll 8
    for (int jj = 0; jj < 64; ++jj) {
        int n = s_seg[j0 + jj];
        if (n != cur) {
            atomicAdd(&hpagg[(long)cur*128 + lane*2],     a0);
            atomicAdd(&hpagg[(long)cur*128 + lane*2 + 1], a1);
            a0 = 0.f; a1 = 0.f; cur = n;
        }
        unsigned v = *(const unsigned*)(hp + (long)s_ids[j0 + jj]*128 + lane*2);
        a0 += __uint_as_float(v << 16);
        a1 += __uint_as_float(v & 0xffff0000u);
    }
    atomicAdd(&hpagg[(long)cur*128 + lane*2],     a0);
    atomicAdd(&hpagg[(long)cur*128 + lane*2 + 1], a1);
}

// ======================= e2: e_new = [B_s|B_r|e]@CEU + eu_b; eagg += segsum(e_new)
template <bool WRITE_E>
__global__ __launch_bounds__(256) void e2_k(
    const bf16* __restrict__ Bs, const bf16* __restrict__ Br, bf16* __restrict__ e_buf,
    const int* __restrict__ ssend, const int* __restrict__ seg, const int* __restrict__ rowptr,
    const bf16* __restrict__ wCEU, const float* __restrict__ eu_b, float* __restrict__ eaggf)
{
    __shared__ __align__(16) bf16 sE[128 * AGG_STRIDE];   // 18432 B
    int tid = threadIdx.x, lane = tid & 63, wv = tid >> 6;
    int l15 = lane & 15, q = lane >> 4;
    int row0 = blockIdx.x*128;
    int wbase = row0 + wv*32;

    int erow[2], sidx[2], ridx[2];
    #pragma unroll
    for (int et = 0; et < 2; ++et) {
        int rc = wbase + et*16 + l15;
        erow[et] = rc;
        sidx[et] = ssend[rc];
        ridx[et] = seg[rc];
    }

    f32x4 acc[2][4];
    {
        float bv[4];
        #pragma unroll
        for (int t = 0; t < 4; ++t) bv[t] = eu_b[t*16 + l15];
        #pragma unroll
        for (int et = 0; et < 2; ++et)
            #pragma unroll
            for (int t = 0; t < 4; ++t) {
                acc[et][t][0]=bv[t]; acc[et][t][1]=bv[t]; acc[et][t][2]=bv[t]; acc[et][t][3]=bv[t];
            }
        #pragma unroll
        for (int c = 0; c < 6; ++c) {
            bf16x8s af[2];
            #pragma unroll
            for (int et = 0; et < 2; ++et) {
                if (c < 2)      af[et] = *(const bf16x8s*)(Bs + (long)sidx[et]*64 + c*32 + q*8);
                else if (c < 4) af[et] = *(const bf16x8s*)(Br + (long)ridx[et]*64 + (c-2)*32 + q*8);
                else            af[et] = *(const bf16x8s*)(e_buf + (long)erow[et]*64 + (c-4)*32 + q*8);
            }
            #pragma unroll
            for (int t = 0; t < 4; ++t) {
                bf16x8s bfv = bfrag(wCEU, c, t, lane);
                #pragma unroll
                for (int et = 0; et < 2; ++et)
                    acc[et][t] = __builtin_amdgcn_mfma_f32_16x16x32_bf16(af[et], bfv, acc[et][t], 0, 0, 0);
            }
        }
    }
    // stage e_new
    #pragma unroll
    for (int et = 0; et < 2; ++et)
        #pragma unroll
        for (int r = 0; r < 4; ++r) {
            int lr = wv*32 + et*16 + q*4 + r;
            #pragma unroll
            for (int t = 0; t < 4; ++t)
                sE[lr*AGG_STRIDE + t*16 + l15] = __float2bfloat16(acc[et][t][r]);
        }
    __syncthreads();

    if (WRITE_E) {
        // vectorized LDS -> global copy of e_new
        #pragma unroll
        for (int w = 0; w < 4; ++w) {
            int ch = w*256 + tid;             // 1024 chunks of 8 bf16
            int rr = ch >> 3, cp = ch & 7;
            *(bf16x8s*)(e_buf + (long)(row0 + rr)*64 + cp*8) =
                *(const bf16x8s*)(sE + rr*AGG_STRIDE + cp*8);
        }
    }

    int col = tid & 63, wpart = tid >> 6;
    int n0 = seg[row0], n1 = seg[row0 + 127];
    for (int n = n0 + wpart; n <= n1; n += 4) {
        int beg = rowptr[n], end = rowptr[n + 1];
        if (beg < row0) beg = row0;
        if (end > row0 + 128) end = row0 + 128;
        if (beg < end) {
            float s = 0.f;
            for (int j = beg; j < end; ++j) s += __bfloat162float(sE[(j - row0)*AGG_STRIDE + col]);
            atomicAdd(&eaggf[(long)n*64 + col], s);
        }
    }
}

// ======================= eemb: e0 embed + bootstrap eagg ==============
__global__ __launch_bounds__(256) void eemb_k(
    const float* __restrict__ e_in, const int* __restrict__ gmap,
    const int* __restrict__ seg, const int* __restrict__ rowptr,
    const bf16* __restrict__ wEE, const float* __restrict__ ee_b,
    float* __restrict__ eaggf, bf16* __restrict__ e_buf)
{
    __shared__ __align__(16) bf16 sE[128 * AGG_STRIDE];
    int tid = threadIdx.x, lane = tid & 63, wv = tid >> 6;
    int l15 = lane & 15, q = lane >> 4;
    int row0 = blockIdx.x*128;

    int em[2];
    #pragma unroll
    for (int et = 0; et < 2; ++et) em[et] = gmap[row0 + wv*32 + et*16 + l15];

    f32x4 acc[2][4];
    float bv[4];
    #pragma unroll
    for (int t = 0; t < 4; ++t) bv[t] = ee_b[t*16 + l15];
    #pragma unroll
    for (int et = 0; et < 2; ++et)
        #pragma unroll
        for (int t = 0; t < 4; ++t) {
            acc[et][t][0]=bv[t]; acc[et][t][1]=bv[t]; acc[et][t][2]=bv[t]; acc[et][t][3]=bv[t];
        }
    {
        bf16x8s af[2];
        #pragma unroll
        for (int et = 0; et < 2; ++et) {
            bf16x8s v = {0,0,0,0,0,0,0,0};
            if (q < 2) v = cvt8(e_in + (long)em[et]*16 + q*8);
            af[et] = v;
        }
        #pragma unroll
        for (int t = 0; t < 4; ++t) {
            bf16x8s bfv = bfrag(wEE, 0, t, lane);
            #pragma unroll
            for (int et = 0; et < 2; ++et)
                acc[et][t] = __builtin_amdgcn_mfma_f32_16x16x32_bf16(af[et], bfv, acc[et][t], 0, 0, 0);
        }
    }
    #pragma unroll
    for (int et = 0; et < 2; ++et)
        #pragma unroll
        for (int r = 0; r < 4; ++r) {
            int lr = wv*32 + et*16 + q*4 + r;
            #pragma unroll
            for (int t = 0; t < 4; ++t)
                sE[lr*AGG_STRIDE + t*16 + l15] = __float2bfloat16(acc[et][t][r]);
        }
    __syncthreads();
    #pragma unroll
    for (int w = 0; w < 4; ++w) {
        int ch = w*256 + tid;
        int rr = ch >> 3, cp = ch & 7;
        *(bf16x8s*)(e_buf + (long)(row0 + rr)*64 + cp*8) =
            *(const bf16x8s*)(sE + rr*AGG_STRIDE + cp*8);
    }
    int col = tid & 63, wpart = tid >> 6;
    int n0 = seg[row0], n1 = seg[row0 + 127];
    for (int n = n0 + wpart; n <= n1; n += 4) {
        int beg = rowptr[n], end = rowptr[n + 1];
        if (beg < row0) beg = row0;
        if (end > row0 + 128) end = row0 + 128;
        if (beg < end) {
            float s = 0.f;
            for (int j = beg; j < end; ++j) s += __bfloat162float(sE[(j - row0)*AGG_STRIDE + col]);
            atomicAdd(&eaggf[(long)n*64 + col], s);
        }
    }
}

// ======================= node kernels =======================
__global__ __launch_bounds__(256) void hemb_k(const float* __restrict__ h_in,
    const bf16* __restrict__ wHE, const float* __restrict__ he_b, bf16* __restrict__ hp)
{
    int tid = threadIdx.x, lane = tid & 63, wv = tid >> 6;
    int l15 = lane & 15, q = lane >> 4;
    int row = blockIdx.x*64 + wv*16 + l15;
    int rc = (row < NN) ? row : NN - 1;
    f32x4 acc[4];
    #pragma unroll
    for (int t = 0; t < 4; ++t) { float b = he_b[t*16 + l15]; acc[t][0]=b; acc[t][1]=b; acc[t][2]=b; acc[t][3]=b; }
    #pragma unroll
    for (int c = 0; c < 4; ++c) {
        bf16x8s af = cvt8(h_in + (long)rc*128 + c*32 + q*8);
        #pragma unroll
        for (int t = 0; t < 4; ++t)
            acc[t] = __builtin_amdgcn_mfma_f32_16x16x32_bf16(af, bfrag(wHE, c, t, lane), acc[t], 0, 0, 0);
    }
    #pragma unroll
    for (int r = 0; r < 4; ++r) {
        int ro = blockIdx.x*64 + wv*16 + q*4 + r;
        if (ro < NN)
            #pragma unroll
            for (int t = 0; t < 4; ++t) hp[(long)ro*128 + t*16 + l15] = __float2bfloat16(acc[t][r]);
    }
}

__global__ __launch_bounds__(256) void pemb_k(const float* __restrict__ p_in,
    const bf16* __restrict__ wPE, const float* __restrict__ pe_b, bf16* __restrict__ hp)
{
    int tid = threadIdx.x, lane = tid & 63, wv = tid >> 6;
    int l15 = lane & 15, q = lane >> 4;
    int row = blockIdx.x*64 + wv*16 + l15;
    int rc = (row < NN) ? row : NN - 1;
    f32x4 acc[4];
    #pragma unroll
    for (int t = 0; t < 4; ++t) { float b = pe_b[t*16 + l15]; acc[t][0]=b; acc[t][1]=b; acc[t][2]=b; acc[t][3]=b; }
    {
        bf16x8s af = {0,0,0,0,0,0,0,0};
        if (q < 2) af = cvt8(p_in + (long)rc*16 + q*8);
        #pragma unroll
        for (int t = 0; t < 4; ++t)
            acc[t] = __builtin_amdgcn_mfma_f32_16x16x32_bf16(af, bfrag(wPE, 0, t, lane), acc[t], 0, 0, 0);
    }
    #pragma unroll
    for (int r = 0; r < 4; ++r) {
        int ro = blockIdx.x*64 + wv*16 + q*4 + r;
        if (ro < NN)
            #pragma unroll
            for (int t = 0; t < 4; ++t) hp[(long)ro*128 + 64 + t*16 + l15] = __float2bfloat16(acc[t][r]);
    }
}

// hfuse: agg = [haggN|paggN|eagg]@HAGG + deg*([h|p]@HMR + hm_b);
//        h_new = [h|agg]@HU + hu_b;  Bs = h_new@EUs, Br = h_new@EUr  (n3 fused)
//        + zero-fuse: clears hpagg[:,0:64] and eagg (last reader) for next layer
__global__ __launch_bounds__(256) void hfuse_k(
    bf16* __restrict__ hp, float* __restrict__ hpagg, float* __restrict__ eagg,
    const int* __restrict__ deg,
    const bf16* __restrict__ wAGG, const bf16* __restrict__ wR, const float* __restrict__ mb,
    const bf16* __restrict__ wU, const float* __restrict__ ub,
    const bf16* __restrict__ wEUs, const bf16* __restrict__ wEUr,
    bf16* __restrict__ Bs, bf16* __restrict__ Br, float* __restrict__ out2)
{
    __shared__ __align__(16) bf16 sAgg[64 * AGG_STRIDE];
    int tid = threadIdx.x, lane = tid & 63, wv = tid >> 6;
    int l15 = lane & 15, q = lane >> 4;
    int row = blockIdx.x*64 + wv*16 + l15;
    int rc = (row < NN) ? row : NN - 1;

    f32x4 aA[4], aR[4];
    #pragma unroll
    for (int t = 0; t < 4; ++t) {
        aA[t][0]=0;aA[t][1]=0;aA[t][2]=0;aA[t][3]=0;
        aR[t][0]=0;aR[t][1]=0;aR[t][2]=0;aR[t][3]=0;
    }
    #pragma unroll
    for (int c = 0; c < 6; ++c) {
        bf16x8s af = (c < 4) ? cvt8(hpagg + (long)rc*128 + c*32 + q*8)
                             : cvt8(eagg + (long)rc*64 + (c-4)*32 + q*8);
        #pragma unroll
        for (int t = 0; t < 4; ++t)
            aA[t] = __builtin_amdgcn_mfma_f32_16x16x32_bf16(af, bfrag(wAGG, c, t, lane), aA[t], 0, 0, 0);
    }
    // zero-fuse: this kernel is the last reader of hpagg[:,0:64] and eagg
    {
        float4 z4 = make_float4(0.f, 0.f, 0.f, 0.f);
        #pragma unroll
        for (int c = 0; c < 2; ++c) {
            *(float4*)(hpagg + (long)rc*128 + c*32 + q*8)     = z4;
            *(float4*)(hpagg + (long)rc*128 + c*32 + q*8 + 4) = z4;
            *(float4*)(eagg  + (long)rc*64  + c*32 + q*8)     = z4;
            *(float4*)(eagg  + (long)rc*64  + c*32 + q*8 + 4) = z4;
        }
    }
    #pragma unroll
    for (int c = 0; c < 4; ++c) {
        bf16x8s af = *(const bf16x8s*)(hp + (long)rc*128 + c*32 + q*8);
        #pragma unroll
        for (int t = 0; t < 4; ++t)
            aR[t] = __builtin_amdgcn_mfma_f32_16x16x32_bf16(af, bfrag(wR, c, t, lane), aR[t], 0, 0, 0);
    }
    float mbv[4];
    #pragma unroll
    for (int t = 0; t < 4; ++t) mbv[t] = mb[t*16 + l15];
    #pragma unroll
    for (int r = 0; r < 4; ++r) {
        int ro = blockIdx.x*64 + wv*16 + q*4 + r;
        float dg = (float)deg[(ro < NN) ? ro : NN - 1];
        #pragma unroll
        for (int t = 0; t < 4; ++t)
            sAgg[(wv*16 + q*4 + r)*AGG_STRIDE + t*16 + l15] =
                __float2bfloat16(aA[t][r] + dg*(aR[t][r] + mbv[t]));
    }
    __syncthreads();
    f32x4 acc[4];
    #pragma unroll
    for (int t = 0; t < 4; ++t) { float b = ub[t*16 + l15]; acc[t][0]=b; acc[t][1]=b; acc[t][2]=b; acc[t][3]=b; }
    #pragma unroll
    for (int c = 0; c < 4; ++c) {
        bf16x8s af = (c < 2) ? *(const bf16x8s*)(hp + (long)rc*128 + c*32 + q*8)
                             : *(const bf16x8s*)(sAgg + (wv*16 + l15)*AGG_STRIDE + (c-2)*32 + q*8);
        #pragma unroll
        for (int t = 0; t < 4; ++t)
            acc[t] = __builtin_amdgcn_mfma_f32_16x16x32_bf16(af, bfrag(wU, c, t, lane), acc[t], 0, 0, 0);
    }
    __syncthreads();   // sAgg reads for HU done; re-stage h_new
    #pragma unroll
    for (int r = 0; r < 4; ++r) {
        int ro = blockIdx.x*64 + wv*16 + q*4 + r;
        #pragma unroll
        for (int t = 0; t < 4; ++t) {
            float fv = acc[t][r];
            bf16 hv = __float2bfloat16(fv);
            sAgg[(wv*16 + q*4 + r)*AGG_STRIDE + t*16 + l15] = hv;
            if (ro < NN) {
                hp[(long)ro*128 + t*16 + l15] = hv;
                if (out2) out2[(long)ro*64 + t*16 + l15] = fv;
            }
        }
    }
    __syncthreads();
    // fused n3: Bs = h_new @ EUs, Br = h_new @ EUr  (K=64)
    f32x4 aBs[4], aBr[4];
    #pragma unroll
    for (int t = 0; t < 4; ++t) {
        aBs[t][0]=0;aBs[t][1]=0;aBs[t][2]=0;aBs[t][3]=0;
        aBr[t][0]=0;aBr[t][1]=0;aBr[t][2]=0;aBr[t][3]=0;
    }
    #pragma unroll
    for (int c = 0; c < 2; ++c) {
        bf16x8s af = *(const bf16x8s*)(sAgg + (wv*16 + l15)*AGG_STRIDE + c*32 + q*8);
        #pragma unroll
        for (int t = 0; t < 4; ++t) {
            aBs[t] = __builtin_amdgcn_mfma_f32_16x16x32_bf16(af, bfrag(wEUs, c, t, lane), aBs[t], 0, 0, 0);
            aBr[t] = __builtin_amdgcn_mfma_f32_16x16x32_bf16(af, bfrag(wEUr, c, t, lane), aBr[t], 0, 0, 0);
        }
    }
    #pragma unroll
    for (int r = 0; r < 4; ++r) {
        int ro = blockIdx.x*64 + wv*16 + q*4 + r;
        if (ro < NN) {
            #pragma unroll
            for (int t = 0; t < 4; ++t) {
                int col = t*16 + l15;
                Bs[(long)ro*64 + col] = __float2bfloat16(aBs[t][r]);
                Br[(long)ro*64 + col] = __float2bfloat16(aBr[t][r]);
            }
        }
    }
}

// pfuse: agg = [paggN|eaggB]@PAGG + deg*(p@PMR + pm_b);  p_new = [p|agg]@PU + pu_b
//        + zero-fuse: clears hpagg[:,64:128] (last reader) for next layer
__global__ __launch_bounds__(256) void pfuse_k(
    bf16* __restrict__ hp, float* __restrict__ hpagg, const float* __restrict__ eagg,
    const int* __restrict__ deg,
    const bf16* __restrict__ wAGG, const bf16* __restrict__ wR, const float* __restrict__ mb,
    const bf16* __restrict__ wU, const float* __restrict__ ub, float* __restrict__ out2)
{
    __shared__ __align__(16) bf16 sAgg[64 * AGG_STRIDE];
    int tid = threadIdx.x, lane = tid & 63, wv = tid >> 6;
    int l15 = lane & 15, q = lane >> 4;
    int row = blockIdx.x*64 + wv*16 + l15;
    int rc = (row < NN) ? row : NN - 1;

    f32x4 aA[4], aR[4];
    #pragma unroll
    for (int t = 0; t < 4; ++t) {
        aA[t][0]=0;aA[t][1]=0;aA[t][2]=0;aA[t][3]=0;
        aR[t][0]=0;aR[t][1]=0;aR[t][2]=0;aR[t][3]=0;
    }
    #pragma unroll
    for (int c = 0; c < 4; ++c) {
        bf16x8s af = (c < 2) ? cvt8(hpagg + (long)rc*128 + 64 + c*32 + q*8)
                             : cvt8(eagg + (long)rc*64 + (c-2)*32 + q*8);
        #pragma unroll
        for (int t = 0; t < 4; ++t)
            aA[t] = __builtin_amdgcn_mfma_f32_16x16x32_bf16(af, bfrag(wAGG, c, t, lane), aA[t], 0, 0, 0);
    }
    // zero-fuse: this kernel is the last reader of hpagg[:,64:128]
    {
        float4 z4 = make_float4(0.f, 0.f, 0.f, 0.f);
        #pragma unroll
        for (int c = 0; c < 2; ++c) {
            *(float4*)(hpagg + (long)rc*128 + 64 + c*32 + q*8)     = z4;
            *(float4*)(hpagg + (long)rc*128 + 64 + c*32 + q*8 + 4) = z4;
        }
    }
    #pragma unroll
    for (int c = 0; c < 2; ++c) {
        bf16x8s af = *(const bf16x8s*)(hp + (long)rc*128 + 64 + c*32 + q*8);
        #pragma unroll
        for (int t = 0; t < 4; ++t)
            aR[t] = __builtin_amdgcn_mfma_f32_16x16x32_bf16(af, bfrag(wR, c, t, lane), aR[t], 0, 0, 0);
    }
    float mbv[4];
    #pragma unroll
    for (int t = 0; t < 4; ++t) mbv[t] = mb[t*16 + l15];
    #pragma unroll
    for (int r = 0; r < 4; ++r) {
        int ro = blockIdx.x*64 + wv*16 + q*4 + r;
        float dg = (float)deg[(ro < NN) ? ro : NN - 1];
        #pragma unroll
        for (int t = 0; t < 4; ++t)
            sAgg[(wv*16 + q*4 + r)*AGG_STRIDE + t*16 + l15] =
                __float2bfloat16(aA[t][r] + dg*(aR[t][r] + mbv[t]));
    }
    __syncthreads();
    f32x4 acc[4];
    #pragma unroll
    for (int t = 0; t < 4; ++t) { float b = ub[t*16 + l15]; acc[t][0]=b; acc[t][1]=b; acc[t][2]=b; acc[t][3]=b; }
    #pragma unroll
    for (int c = 0; c < 4; ++c) {
        bf16x8s af = (c < 2) ? *(const bf16x8s*)(hp + (long)rc*128 + 64 + c*32 + q*8)
                             : *(const bf16x8s*)(sAgg + (wv*16 + l15)*AGG_STRIDE + (c-2)*32 + q*8);
        #pragma unroll
        for (int t = 0; t < 4; ++t)
            acc[t] = __builtin_amdgcn_mfma_f32_16x16x32_bf16(af, bfrag(wU, c, t, lane), acc[t], 0, 0, 0);
    }
    #pragma unroll
    for (int r = 0; r < 4; ++r) {
        int ro = blockIdx.x*64 + wv*16 + q*4 + r;
        if (ro < NN) {
            #pragma unroll
            for (int t = 0; t < 4; ++t) {
                float fv = acc[t][r];
                hp[(long)ro*128 + 64 + t*16 + l15] = __float2bfloat16(fv);
                if (out2) out2[(long)ro*64 + t*16 + l15] = fv;
            }
        }
    }
}

// ======================= launch =======================
extern "C" void kernel_launch(void* const* d_in, const int* in_sizes, int n_in,
                              void* d_out, int out_size, void* d_ws, size_t ws_size,
                              hipStream_t stream)
{
    (void)in_sizes; (void)n_in; (void)out_size; (void)ws_size;
    const float* h_in = (const float*)d_in[0];
    const float* e_in = (const float*)d_in[1];
    const float* p_in = (const float*)d_in[2];
    const int*  ei   = (const int*)d_in[3];
    const int* send = ei;
    const int* rec  = ei + NE;
    const float* he_W = (const float*)d_in[4];  const float* he_b = (const float*)d_in[5];
    const float* ee_W = (const float*)d_in[6];  const float* ee_b = (const float*)d_in[7];
    const float* pe_W = (const float*)d_in[8];  const float* pe_b = (const float*)d_in[9];
    const float* hm_W = (const float*)d_in[10]; const float* hm_b = (const float*)d_in[11];
    const float* hu_W = (const float*)d_in[12]; const float* hu_b = (const float*)d_in[13];
    const float* eu_W = (const float*)d_in[14]; const float* eu_b = (const float*)d_in[15];
    const float* pm_W = (const float*)d_in[16]; const float* pm_b = (const float*)d_in[17];
    const float* pu_W = (const float*)d_in[18]; const float* pu_b = (const float*)d_in[19];

    char* ws = (char*)d_ws;
    bf16* e_buf  = (bf16*)(ws + OFF_E);
    bf16* hp     = (bf16*)(ws + OFF_HP);
    float* hpagg = (float*)(ws + OFF_HPAGG);
    float* eaggA = (float*)(ws + OFF_EAGGA);
    float* eaggB = (float*)(ws + OFF_EAGGB);
    bf16* Bs     = (bf16*)(ws + OFF_BS);
    bf16* Br     = (bf16*)(ws + OFF_BR);
    bf16* wf     = (bf16*)(ws + OFF_WFMT);
    int* rowptr  = (int*)(ws + OFF_ROWPTR);
    int* colidx  = (int*)(ws + OFF_COLIDX);
    int* ssend   = (int*)(ws + OFF_SSEND);
    int* segarr  = (int*)(ws + OFF_SEG);
    int* cnt     = (int*)(ws + OFF_CNT);
    int* bsum    = (int*)(ws + OFF_BSUM);
    float* dout  = (float*)d_out;

    const int EB   = NE / 256;          // 3125
    const int EB2  = NE / 128;          // 6250
    const int NB64 = (NN + 63) / 64;    // 782

    // CSR build; cnt ends as deg
    (void)hipMemsetAsync(cnt, 0, NN * sizeof(int), stream);
    hist_k<<<EB, 256, 0, stream>>>(rec, cnt);
    scan1_k<<<SCAN_B, 256, 0, stream>>>(cnt, bsum);
    scan2_k<<<1, 256, 0, stream>>>(bsum);
    scan3_k<<<SCAN_B, 256, 0, stream>>>(cnt, bsum, rowptr);
    (void)hipMemsetAsync(cnt, 0, NN * sizeof(int), stream);
    scatter_k<<<EB, 256, 0, stream>>>(rec, rowptr, cnt, colidx);
    fillseg_k<<<EB, 256, 0, stream>>>(rowptr, colidx, send, segarr, ssend);

    wfmt_k<<<39, 256, 0, stream>>>(he_W, ee_W, pe_W, hm_W, hu_W, eu_W, pm_W, pu_W, wf);

    // zero hpagg + eaggA + eaggB in one contiguous memset (zero-fuse maintains it per layer)
    (void)hipMemsetAsync(hpagg, 0, (long)NN*(128 + 64 + 64)*sizeof(float), stream);

    // embeddings
    hemb_k<<<NB64, 256, 0, stream>>>(h_in, wf + FW_HE, he_b, hp);
    pemb_k<<<NB64, 256, 0, stream>>>(p_in, wf + FW_PE, pe_b, hp);
    eemb_k<<<EB2, 256, 0, stream>>>(e_in, colidx, segarr, rowptr,
        wf + FW_EE, ee_b, eaggA, e_buf);

    float* eA = eaggA;
    float* eB = eaggB;
    for (int i = 0; i < 4; ++i) {
        long base = FW_L0 + (long)i*LSTR;
        // raw neighbor sums of h,p (hpagg zeroed by prev layer's hfuse/pfuse)
        gsum_k<<<EB, 256, 0, stream>>>(hp, ssend, segarr, hpagg);
        // h update (agg compose + A_rec + hu + n3, fused; zeros hpagg[:,0:64] + eA)
        hfuse_k<<<NB64, 256, 0, stream>>>(hp, hpagg, eA, cnt,
            wf + base + R_HAGG, wf + base + R_HMR, hm_b + i*64,
            wf + base + R_HU, hu_b + i*64,
            wf + base + R_EUS, wf + base + R_EUR, Bs, Br,
            (i == 3) ? dout : nullptr);
        // e update + eagg segsum (eB pre-zeroed: init memset for i=0, hfuse_{i-1} for i>0)
        if (i < 3)
            e2_k<true><<<EB2, 256, 0, stream>>>(Bs, Br, e_buf, ssend, segarr, rowptr,
                wf + base + R_CEU, eu_b + i*64, eB);
        else
            e2_k<false><<<EB2, 256, 0, stream>>>(Bs, Br, e_buf, ssend, segarr, rowptr,
                wf + base + R_CEU, eu_b + i*64, eB);
        // p update (agg compose + C_r + pu, fused; zeros hpagg[:,64:128])
        pfuse_k<<<NB64, 256, 0, stream>>>(hp, hpagg, eB, cnt,
            wf + base + R_PAGG, wf + base + R_PMR, pm_b + i*64,
            wf + base + R_PU, pu_b + i*64, (i == 3) ? dout + (long)NN*64 : nullptr);
        float* tmp = eA; eA = eB; eB = tmp;
    }
}

// Round 4
// 951.041 us; speedup vs baseline: 1.5394x; 1.0634x over previous
//
#include <hip/hip_runtime.h>
#include <hip/hip_bf16.h>

#define NN 50000
#define NE 800000

typedef __hip_bfloat16 bf16;
typedef __attribute__((ext_vector_type(8))) short bf16x8s;   // 8 bf16 = 4 VGPRs
typedef __attribute__((ext_vector_type(4))) float f32x4;

// ---- workspace layout (bytes) ----
#define OFF_HP     0L            // hp [NN,128] bf16 : cols 0:64 = h, 64:128 = p
#define OFF_HSUM   12800000L     // hsum [NN,64] f32 (segsum of h over in-edges, by sender)
#define OFF_PSUM   25600000L     // psum [NN,64] f32
#define OFF_ESUM   38400000L     // esum [NN,16] f32 (segsum of raw e_in)
#define OFF_EAGGA  41600000L     // eaggA [NN,64] f32
#define OFF_EAGGB  54400000L     // eaggB [NN,64] f32
#define OFF_WFMT   67200000L     // formatted weights (516096 B)
#define OFF_ROWPTR 67716096L     // (NN+1) int
#define OFF_COLIDX 67916100L     // NE int (sorted j -> original edge id)
#define OFF_SSEND  71116100L     // NE int (send of sorted edge j)
#define OFF_SEG    74316100L     // NE int (rec of sorted edge j)
#define OFF_CNT    77516100L     // NN int (ends as deg)
#define OFF_BSUM   77716100L     // SCAN_B int block sums

#define SCAN_B 196               // ceil(NN/256)

// ---- formatted-weight element offsets (bf16 elems) ----
#define FW_HE 0
#define FW_EE 8192
#define FW_PE 10240
#define FW_L0 12288
#define LSTR  61440
#define R_HAGG 0        // [hm rows 0:128 ; hm rows 256:320]  K=192  (in: [hsum|psum|eagg])
#define R_HMR  12288    // hm rows 128:256                    K=128  (in: [h|p])
#define R_HU   20480    // hu [128,64]
#define R_EUS  28672    // eu rows 0:64    K=64  (in: hsum_{i+1})
#define R_EUR  32768    // eu rows 64:128  K=64  (in: h_{i+1})
#define R_EUE  36864    // eu rows 128:192 K=64  (in: eagg_i)
#define R_PAGG 40960    // [pm rows 0:64 ; pm rows 128:192]   K=128  (in: [psum|eagg_{i+1}])
#define R_PMR  49152    // pm rows 64:128                     K=64   (in: p)
#define R_PU   53248    // pu [128,64]

#define AGG_STRIDE 72

__device__ __forceinline__ bf16x8s bfrag(const bf16* w, int c, int t, int lane) {
    return *(const bf16x8s*)(w + ((long)(c*4 + t)*64 + lane)*8);
}
__device__ __forceinline__ bf16x8s cvt8(const float* fp) {
    float4 f0 = ((const float4*)fp)[0];
    float4 f1 = ((const float4*)fp)[1];
    bf16 tmp[8];
    tmp[0]=__float2bfloat16(f0.x); tmp[1]=__float2bfloat16(f0.y);
    tmp[2]=__float2bfloat16(f0.z); tmp[3]=__float2bfloat16(f0.w);
    tmp[4]=__float2bfloat16(f1.x); tmp[5]=__float2bfloat16(f1.y);
    tmp[6]=__float2bfloat16(f1.z); tmp[7]=__float2bfloat16(f1.w);
    return *(const bf16x8s*)tmp;
}

// ======================= weight formatting =======================
__global__ __launch_bounds__(256) void wfmt_k(
    const float* __restrict__ he, const float* __restrict__ ee, const float* __restrict__ pe,
    const float* __restrict__ hm, const float* __restrict__ hu, const float* __restrict__ eu,
    const float* __restrict__ pm, const float* __restrict__ pu, bf16* __restrict__ wf)
{
    int s = blockIdx.x;
    const float* src = nullptr; int rowoff = 0, Ksrc = 0, Kpad = 0, mode = 0, split = 0, gap = 0; long doff = 0;
    if      (s == 0) { src = he; Ksrc = 128; Kpad = 128; doff = FW_HE; }
    else if (s == 1) { src = ee; Ksrc = 16;  Kpad = 32;  doff = FW_EE; }
    else if (s == 2) { src = pe; Ksrc = 16;  Kpad = 32;  doff = FW_PE; }
    else {
        int i = (s - 3) / 9, g = (s - 3) % 9;
        long base = FW_L0 + (long)i*LSTR;
        const float* HM = hm + (long)i*320*64;
        const float* HU = hu + (long)i*128*64;
        const float* EU = eu + (long)i*192*64;
        const float* PM = pm + (long)i*192*64;
        const float* PU = pu + (long)i*128*64;
        switch (g) {
          case 0:  src=HM; mode=4; split=128; gap=128; Kpad=192; doff=base+R_HAGG; break;
          case 1:  src=HM; rowoff=128; Ksrc=128; Kpad=128; doff=base+R_HMR;  break;
          case 2:  src=HU; rowoff=0;   Ksrc=128; Kpad=128; doff=base+R_HU;   break;
          case 3:  src=EU; rowoff=0;   Ksrc=64;  Kpad=64;  doff=base+R_EUS;  break;
          case 4:  src=EU; rowoff=64;  Ksrc=64;  Kpad=64;  doff=base+R_EUR;  break;
          case 5:  src=EU; rowoff=128; Ksrc=64;  Kpad=64;  doff=base+R_EUE;  break;
          case 6:  src=PM; mode=4; split=64; gap=64; Kpad=128; doff=base+R_PAGG; break;
          case 7:  src=PM; rowoff=64;  Ksrc=64;  Kpad=64;  doff=base+R_PMR;  break;
          default: src=PU; rowoff=0;   Ksrc=128; Kpad=128; doff=base+R_PU;   break;
        }
    }
    int total = Kpad * 64;
    for (int idx = threadIdx.x; idx < total; idx += 256) {
        int j = idx & 7, l = (idx >> 3) & 63, ct = idx >> 9;
        int c = ct >> 2, t = ct & 3;
        int k = c*32 + (l >> 4)*8 + j;
        int n = t*16 + (l & 15);
        float v;
        if (mode == 4) v = src[(long)(k + (k >= split ? gap : 0))*64 + n];
        else           v = (k < Ksrc) ? src[(long)(rowoff + k)*64 + n] : 0.f;
        wf[doff + idx] = __float2bfloat16(v);
    }
}

// ======================= CSR build =======================
__global__ __launch_bounds__(256) void hist_k(const int* __restrict__ rec, int* __restrict__ cnt)
{
    int e = blockIdx.x*256 + threadIdx.x;
    if (e < NE) atomicAdd(&cnt[rec[e]], 1);
}

__global__ __launch_bounds__(256) void scan1_k(const int* __restrict__ cnt, int* __restrict__ bsum)
{
    __shared__ int sdata[256];
    int tid = threadIdx.x;
    int i = blockIdx.x*256 + tid;
    sdata[tid] = (i < NN) ? cnt[i] : 0;
    __syncthreads();
    #pragma unroll
    for (int off = 128; off > 0; off >>= 1) {
        if (tid < off) sdata[tid] += sdata[tid + off];
        __syncthreads();
    }
    if (tid == 0) bsum[blockIdx.x] = sdata[0];
}

__global__ __launch_bounds__(256) void scan2_k(int* __restrict__ bsum)
{
    __shared__ int sdata[256];
    int tid = threadIdx.x;
    int v = (tid < SCAN_B) ? bsum[tid] : 0;
    sdata[tid] = v;
    __syncthreads();
    #pragma unroll
    for (int off = 1; off < 256; off <<= 1) {
        int t = (tid >= off) ? sdata[tid - off] : 0;
        __syncthreads();
        sdata[tid] += t;
        __syncthreads();
    }
    if (tid < SCAN_B) bsum[tid] = sdata[tid] - v;   // exclusive
}

__global__ __launch_bounds__(256) void scan3_k(const int* __restrict__ cnt,
    const int* __restrict__ bsum, int* __restrict__ rowptr)
{
    __shared__ int sdata[256];
    int tid = threadIdx.x;
    int i = blockIdx.x*256 + tid;
    sdata[tid] = (i < NN) ? cnt[i] : 0;
    __syncthreads();
    #pragma unroll
    for (int off = 1; off < 256; off <<= 1) {
        int t = (tid >= off) ? sdata[tid - off] : 0;
        __syncthreads();
        sdata[tid] += t;
        __syncthreads();
    }
    if (i < NN) rowptr[i + 1] = sdata[tid] + bsum[blockIdx.x];
    if (i == 0) rowptr[0] = 0;
}

__global__ __launch_bounds__(256) void scatter_k(const int* __restrict__ rec,
    const int* __restrict__ rowptr, int* __restrict__ cursor, int* __restrict__ colidx)
{
    int e = blockIdx.x*256 + threadIdx.x;
    if (e < NE) {
        int r = rec[e];
        int pos = atomicAdd(&cursor[r], 1);
        colidx[rowptr[r] + pos] = e;
    }
}

__global__ __launch_bounds__(256) void fillseg_k(const int* __restrict__ rowptr,
    const int* __restrict__ colidx, const int* __restrict__ send,
    int* __restrict__ seg, int* __restrict__ ssend)
{
    int j = blockIdx.x*256 + threadIdx.x;
    if (j < NE) {
        int lo = 0, hi = NN - 1;
        while (lo < hi) {
            int mid = (lo + hi + 1) >> 1;
            if (rowptr[mid] <= j) lo = mid; else hi = mid - 1;
        }
        seg[j] = lo;
        ssend[j] = send[colidx[j]];
    }
}

// ======================= gsum64: out[n,0:64] += segsum of hp[ssend, coff:coff+64] ==========
__global__ __launch_bounds__(256) void gsum64_k(const bf16* __restrict__ hp, int coff,
    const int* __restrict__ ssend, const int* __restrict__ seg, float* __restrict__ out)
{
    __shared__ int s_ids[256];
    __shared__ int s_seg[256];
    int tid = threadIdx.x, lane = tid & 63, wv = tid >> 6;
    int gbase = blockIdx.x*256;
    s_ids[tid] = ssend[gbase + tid];
    s_seg[tid] = seg[gbase + tid];
    __syncthreads();
    int j0 = wv*64;
    float a0 = 0.f;
    int cur = s_seg[j0];
    #pragma unroll 8
    for (int jj = 0; jj < 64; ++jj) {
        int n = s_seg[j0 + jj];
        if (n != cur) { atomicAdd(&out[(long)cur*64 + lane], a0); a0 = 0.f; cur = n; }
        unsigned short v = *(const unsigned short*)(hp + (long)s_ids[j0 + jj]*128 + coff + lane);
        a0 += __uint_as_float(((unsigned)v) << 16);
    }
    atomicAdd(&out[(long)cur*64 + lane], a0);
}

// ======================= esum: segsum of raw e_in (16-wide) ==============
__global__ __launch_bounds__(256) void esum_k(const float* __restrict__ e_in,
    const int* __restrict__ colidx, const int* __restrict__ seg, float* __restrict__ esum)
{
    __shared__ int s_ids[256];
    __shared__ int s_seg[256];
    int tid = threadIdx.x;
    int gbase = blockIdx.x*256;
    s_ids[tid] = colidx[gbase + tid];
    s_seg[tid] = seg[gbase + tid];
    __syncthreads();
    int grp = tid >> 4;          // 16 groups of 16 lanes
    int c   = tid & 15;
    int j0 = grp*16;
    float a = 0.f;
    int cur = s_seg[j0];
    #pragma unroll 4
    for (int jj = 0; jj < 16; ++jj) {
        int n = s_seg[j0 + jj];
        if (n != cur) { atomicAdd(&esum[(long)cur*16 + c], a); a = 0.f; cur = n; }
        a += e_in[(long)s_ids[j0 + jj]*16 + c];
    }
    atomicAdd(&esum[(long)cur*16 + c], a);
}

// ======================= eembn: eagg0 = esum@EE + deg*ee_b (node-level) ==========
__global__ __launch_bounds__(256) void eembn_k(const float* __restrict__ esum,
    const int* __restrict__ deg, const bf16* __restrict__ wEE, const float* __restrict__ ee_b,
    float* __restrict__ eagg)
{
    int tid = threadIdx.x, lane = tid & 63, wv = tid >> 6;
    int l15 = lane & 15, q = lane >> 4;
    int row = blockIdx.x*64 + wv*16 + l15;
    int rc = (row < NN) ? row : NN - 1;
    f32x4 acc[4];
    #pragma unroll
    for (int t = 0; t < 4; ++t) { acc[t][0]=0; acc[t][1]=0; acc[t][2]=0; acc[t][3]=0; }
    {
        bf16x8s af = {0,0,0,0,0,0,0,0};
        if (q < 2) af = cvt8(esum + (long)rc*16 + q*8);
        #pragma unroll
        for (int t = 0; t < 4; ++t)
            acc[t] = __builtin_amdgcn_mfma_f32_16x16x32_bf16(af, bfrag(wEE, 0, t, lane), acc[t], 0, 0, 0);
    }
    float bv[4];
    #pragma unroll
    for (int t = 0; t < 4; ++t) bv[t] = ee_b[t*16 + l15];
    #pragma unroll
    for (int r = 0; r < 4; ++r) {
        int ro = blockIdx.x*64 + wv*16 + q*4 + r;
        if (ro < NN) {
            float dg = (float)deg[ro];
            #pragma unroll
            for (int t = 0; t < 4; ++t)
                eagg[(long)ro*64 + t*16 + l15] = acc[t][r] + dg*bv[t];
        }
    }
}

// ======================= node embed kernels =======================
__global__ __launch_bounds__(256) void hemb_k(const float* __restrict__ h_in,
    const bf16* __restrict__ wHE, const float* __restrict__ he_b, bf16* __restrict__ hp)
{
    int tid = threadIdx.x, lane = tid & 63, wv = tid >> 6;
    int l15 = lane & 15, q = lane >> 4;
    int row = blockIdx.x*64 + wv*16 + l15;
    int rc = (row < NN) ? row : NN - 1;
    f32x4 acc[4];
    #pragma unroll
    for (int t = 0; t < 4; ++t) { float b = he_b[t*16 + l15]; acc[t][0]=b; acc[t][1]=b; acc[t][2]=b; acc[t][3]=b; }
    #pragma unroll
    for (int c = 0; c < 4; ++c) {
        bf16x8s af = cvt8(h_in + (long)rc*128 + c*32 + q*8);
        #pragma unroll
        for (int t = 0; t < 4; ++t)
            acc[t] = __builtin_amdgcn_mfma_f32_16x16x32_bf16(af, bfrag(wHE, c, t, lane), acc[t], 0, 0, 0);
    }
    #pragma unroll
    for (int r = 0; r < 4; ++r) {
        int ro = blockIdx.x*64 + wv*16 + q*4 + r;
        if (ro < NN)
            #pragma unroll
            for (int t = 0; t < 4; ++t) hp[(long)ro*128 + t*16 + l15] = __float2bfloat16(acc[t][r]);
    }
}

__global__ __launch_bounds__(256) void pemb_k(const float* __restrict__ p_in,
    const bf16* __restrict__ wPE, const float* __restrict__ pe_b, bf16* __restrict__ hp)
{
    int tid = threadIdx.x, lane = tid & 63, wv = tid >> 6;
    int l15 = lane & 15, q = lane >> 4;
    int row = blockIdx.x*64 + wv*16 + l15;
    int rc = (row < NN) ? row : NN - 1;
    f32x4 acc[4];
    #pragma unroll
    for (int t = 0; t < 4; ++t) { float b = pe_b[t*16 + l15]; acc[t][0]=b; acc[t][1]=b; acc[t][2]=b; acc[t][3]=b; }
    {
        bf16x8s af = {0,0,0,0,0,0,0,0};
        if (q < 2) af = cvt8(p_in + (long)rc*16 + q*8);
        #pragma unroll
        for (int t = 0; t < 4; ++t)
            acc[t] = __builtin_amdgcn_mfma_f32_16x16x32_bf16(af, bfrag(wPE, 0, t, lane), acc[t], 0, 0, 0);
    }
    #pragma unroll
    for (int r = 0; r < 4; ++r) {
        int ro = blockIdx.x*64 + wv*16 + q*4 + r;
        if (ro < NN)
            #pragma unroll
            for (int t = 0; t < 4; ++t) hp[(long)ro*128 + 64 + t*16 + l15] = __float2bfloat16(acc[t][r]);
    }
}

// hfuse: agg = [hsum|psum|eagg]@HAGG + deg*([h|p]@HMR + hm_b);  h_new = [h|agg]@HU + hu_b
//        zero-fuse: clears hsum (last reader) for the next gsum
__global__ __launch_bounds__(256) void hfuse_k(
    bf16* __restrict__ hp, float* __restrict__ hsum, const float* __restrict__ psum,
    const float* __restrict__ eagg, const int* __restrict__ deg,
    const bf16* __restrict__ wAGG, const bf16* __restrict__ wR, const float* __restrict__ mb,
    const bf16* __restrict__ wU, const float* __restrict__ ub, float* __restrict__ out2)
{
    __shared__ __align__(16) bf16 sAgg[64 * AGG_STRIDE];
    int tid = threadIdx.x, lane = tid & 63, wv = tid >> 6;
    int l15 = lane & 15, q = lane >> 4;
    int row = blockIdx.x*64 + wv*16 + l15;
    int rc = (row < NN) ? row : NN - 1;

    f32x4 aA[4], aR[4];
    #pragma unroll
    for (int t = 0; t < 4; ++t) {
        aA[t][0]=0;aA[t][1]=0;aA[t][2]=0;aA[t][3]=0;
        aR[t][0]=0;aR[t][1]=0;aR[t][2]=0;aR[t][3]=0;
    }
    #pragma unroll
    for (int c = 0; c < 6; ++c) {
        bf16x8s af = (c < 2) ? cvt8(hsum + (long)rc*64 + c*32 + q*8)
                   : (c < 4) ? cvt8(psum + (long)rc*64 + (c-2)*32 + q*8)
                             : cvt8(eagg + (long)rc*64 + (c-4)*32 + q*8);
        #pragma unroll
        for (int t = 0; t < 4; ++t)
            aA[t] = __builtin_amdgcn_mfma_f32_16x16x32_bf16(af, bfrag(wAGG, c, t, lane), aA[t], 0, 0, 0);
    }
    // zero-fuse hsum (owner rows only)
    if (row < NN) {
        float4 z4 = make_float4(0.f, 0.f, 0.f, 0.f);
        #pragma unroll
        for (int c = 0; c < 2; ++c) {
            *(float4*)(hsum + (long)rc*64 + c*32 + q*8)     = z4;
            *(float4*)(hsum + (long)rc*64 + c*32 + q*8 + 4) = z4;
        }
    }
    #pragma unroll
    for (int c = 0; c < 4; ++c) {
        bf16x8s af = *(const bf16x8s*)(hp + (long)rc*128 + c*32 + q*8);
        #pragma unroll
        for (int t = 0; t < 4; ++t)
            aR[t] = __builtin_amdgcn_mfma_f32_16x16x32_bf16(af, bfrag(wR, c, t, lane), aR[t], 0, 0, 0);
    }
    float mbv[4];
    #pragma unroll
    for (int t = 0; t < 4; ++t) mbv[t] = mb[t*16 + l15];
    #pragma unroll
    for (int r = 0; r < 4; ++r) {
        int ro = blockIdx.x*64 + wv*16 + q*4 + r;
        float dg = (float)deg[(ro < NN) ? ro : NN - 1];
        #pragma unroll
        for (int t = 0; t < 4; ++t)
            sAgg[(wv*16 + q*4 + r)*AGG_STRIDE + t*16 + l15] =
                __float2bfloat16(aA[t][r] + dg*(aR[t][r] + mbv[t]));
    }
    __syncthreads();
    f32x4 acc[4];
    #pragma unroll
    for (int t = 0; t < 4; ++t) { float b = ub[t*16 + l15]; acc[t][0]=b; acc[t][1]=b; acc[t][2]=b; acc[t][3]=b; }
    #pragma unroll
    for (int c = 0; c < 4; ++c) {
        bf16x8s af = (c < 2) ? *(const bf16x8s*)(hp + (long)rc*128 + c*32 + q*8)
                             : *(const bf16x8s*)(sAgg + (wv*16 + l15)*AGG_STRIDE + (c-2)*32 + q*8);
        #pragma unroll
        for (int t = 0; t < 4; ++t)
            acc[t] = __builtin_amdgcn_mfma_f32_16x16x32_bf16(af, bfrag(wU, c, t, lane), acc[t], 0, 0, 0);
    }
    #pragma unroll
    for (int r = 0; r < 4; ++r) {
        int ro = blockIdx.x*64 + wv*16 + q*4 + r;
        if (ro < NN) {
            #pragma unroll
            for (int t = 0; t < 4; ++t) {
                float fv = acc[t][r];
                hp[(long)ro*128 + t*16 + l15] = __float2bfloat16(fv);
                if (out2) out2[(long)ro*64 + t*16 + l15] = fv;
            }
        }
    }
}

// pfuse: eaggNew = hsumN@EUS + deg*(h_new@EUR + eu_b) + eaggIn@EUE   (stored fp32)
//        agg = [psum|eaggNew]@PAGG + deg*(p@PMR + pm_b);  p_new = [p|agg]@PU + pu_b
//        zero-fuse: clears psum (last reader)
__global__ __launch_bounds__(256) void pfuse_k(
    bf16* __restrict__ hp, const float* __restrict__ hsumN, float* __restrict__ psum,
    const float* __restrict__ eaggIn, float* __restrict__ eaggOut, const int* __restrict__ deg,
    const bf16* __restrict__ wEUS, const bf16* __restrict__ wEUR, const bf16* __restrict__ wEUE,
    const float* __restrict__ eub,
    const bf16* __restrict__ wAGG, const bf16* __restrict__ wR, const float* __restrict__ mb,
    const bf16* __restrict__ wU, const float* __restrict__ ub, float* __restrict__ out2)
{
    __shared__ __align__(16) bf16 sE[64 * AGG_STRIDE];
    __shared__ __align__(16) bf16 sAgg[64 * AGG_STRIDE];
    int tid = threadIdx.x, lane = tid & 63, wv = tid >> 6;
    int l15 = lane & 15, q = lane >> 4;
    int row = blockIdx.x*64 + wv*16 + l15;
    int rc = (row < NN) ? row : NN - 1;

    // ---- eagg recurrence ----
    f32x4 aE[4], aH[4];
    #pragma unroll
    for (int t = 0; t < 4; ++t) {
        aE[t][0]=0;aE[t][1]=0;aE[t][2]=0;aE[t][3]=0;
        aH[t][0]=0;aH[t][1]=0;aH[t][2]=0;aH[t][3]=0;
    }
    #pragma unroll
    for (int c = 0; c < 4; ++c) {
        bf16x8s af = (c < 2) ? cvt8(hsumN + (long)rc*64 + c*32 + q*8)
                             : cvt8(eaggIn + (long)rc*64 + (c-2)*32 + q*8);
        #pragma unroll
        for (int t = 0; t < 4; ++t) {
            bf16x8s w = (c < 2) ? bfrag(wEUS, c, t, lane) : bfrag(wEUE, c-2, t, lane);
            aE[t] = __builtin_amdgcn_mfma_f32_16x16x32_bf16(af, w, aE[t], 0, 0, 0);
        }
    }
    #pragma unroll
    for (int c = 0; c < 2; ++c) {
        bf16x8s af = *(const bf16x8s*)(hp + (long)rc*128 + c*32 + q*8);   // h_new
        #pragma unroll
        for (int t = 0; t < 4; ++t)
            aH[t] = __builtin_amdgcn_mfma_f32_16x16x32_bf16(af, bfrag(wEUR, c, t, lane), aH[t], 0, 0, 0);
    }
    float ebv[4];
    #pragma unroll
    for (int t = 0; t < 4; ++t) ebv[t] = eub[t*16 + l15];
    #pragma unroll
    for (int r = 0; r < 4; ++r) {
        int ro = blockIdx.x*64 + wv*16 + q*4 + r;
        float dg = (float)deg[(ro < NN) ? ro : NN - 1];
        #pragma unroll
        for (int t = 0; t < 4; ++t) {
            float ev = aE[t][r] + dg*(aH[t][r] + ebv[t]);
            sE[(wv*16 + q*4 + r)*AGG_STRIDE + t*16 + l15] = __float2bfloat16(ev);
            if (ro < NN) eaggOut[(long)ro*64 + t*16 + l15] = ev;
        }
    }
    __syncthreads();

    // ---- p aggregate compose ----
    f32x4 aA[4], aR[4];
    #pragma unroll
    for (int t = 0; t < 4; ++t) {
        aA[t][0]=0;aA[t][1]=0;aA[t][2]=0;aA[t][3]=0;
        aR[t][0]=0;aR[t][1]=0;aR[t][2]=0;aR[t][3]=0;
    }
    #pragma unroll
    for (int c = 0; c < 4; ++c) {
        bf16x8s af = (c < 2) ? cvt8(psum + (long)rc*64 + c*32 + q*8)
                             : *(const bf16x8s*)(sE + (wv*16 + l15)*AGG_STRIDE + (c-2)*32 + q*8);
        #pragma unroll
        for (int t = 0; t < 4; ++t)
            aA[t] = __builtin_amdgcn_mfma_f32_16x16x32_bf16(af, bfrag(wAGG, c, t, lane), aA[t], 0, 0, 0);
    }
    // zero-fuse psum (owner rows only)
    if (row < NN) {
        float4 z4 = make_float4(0.f, 0.f, 0.f, 0.f);
        #pragma unroll
        for (int c = 0; c < 2; ++c) {
            *(float4*)(psum + (long)rc*64 + c*32 + q*8)     = z4;
            *(float4*)(psum + (long)rc*64 + c*32 + q*8 + 4) = z4;
        }
    }
    #pragma unroll
    for (int c = 0; c < 2; ++c) {
        bf16x8s af = *(const bf16x8s*)(hp + (long)rc*128 + 64 + c*32 + q*8);
        #pragma unroll
        for (int t = 0; t < 4; ++t)
            aR[t] = __builtin_amdgcn_mfma_f32_16x16x32_bf16(af, bfrag(wR, c, t, lane), aR[t], 0, 0, 0);
    }
    float mbv[4];
    #pragma unroll
    for (int t = 0; t < 4; ++t) mbv[t] = mb[t*16 + l15];
    #pragma unroll
    for (int r = 0; r < 4; ++r) {
        int ro = blockIdx.x*64 + wv*16 + q*4 + r;
        float dg = (float)deg[(ro < NN) ? ro : NN - 1];
        #pragma unroll
        for (int t = 0; t < 4; ++t)
            sAgg[(wv*16 + q*4 + r)*AGG_STRIDE + t*16 + l15] =
                __float2bfloat16(aA[t][r] + dg*(aR[t][r] + mbv[t]));
    }
    __syncthreads();
    f32x4 acc[4];
    #pragma unroll
    for (int t = 0; t < 4; ++t) { float b = ub[t*16 + l15]; acc[t][0]=b; acc[t][1]=b; acc[t][2]=b; acc[t][3]=b; }
    #pragma unroll
    for (int c = 0; c < 4; ++c) {
        bf16x8s af = (c < 2) ? *(const bf16x8s*)(hp + (long)rc*128 + 64 + c*32 + q*8)
                             : *(const bf16x8s*)(sAgg + (wv*16 + l15)*AGG_STRIDE + (c-2)*32 + q*8);
        #pragma unroll
        for (int t = 0; t < 4; ++t)
            acc[t] = __builtin_amdgcn_mfma_f32_16x16x32_bf16(af, bfrag(wU, c, t, lane), acc[t], 0, 0, 0);
    }
    #pragma unroll
    for (int r = 0; r < 4; ++r) {
        int ro = blockIdx.x*64 + wv*16 + q*4 + r;
        if (ro < NN) {
            #pragma unroll
            for (int t = 0; t < 4; ++t) {
                float fv = acc[t][r];
                hp[(long)ro*128 + 64 + t*16 + l15] = __float2bfloat16(fv);
                if (out2) out2[(long)ro*64 + t*16 + l15] = fv;
            }
        }
    }
}

// ======================= launch =======================
extern "C" void kernel_launch(void* const* d_in, const int* in_sizes, int n_in,
                              void* d_out, int out_size, void* d_ws, size_t ws_size,
                              hipStream_t stream)
{
    (void)in_sizes; (void)n_in; (void)out_size; (void)ws_size;
    const float* h_in = (const float*)d_in[0];
    const float* e_in = (const float*)d_in[1];
    const float* p_in = (const float*)d_in[2];
    const int*  ei   = (const int*)d_in[3];
    const int* send = ei;
    const int* rec  = ei + NE;
    const float* he_W = (const float*)d_in[4];  const float* he_b = (const float*)d_in[5];
    const float* ee_W = (const float*)d_in[6];  const float* ee_b = (const float*)d_in[7];
    const float* pe_W = (const float*)d_in[8];  const float* pe_b = (const float*)d_in[9];
    const float* hm_W = (const float*)d_in[10]; const float* hm_b = (const float*)d_in[11];
    const float* hu_W = (const float*)d_in[12]; const float* hu_b = (const float*)d_in[13];
    const float* eu_W = (const float*)d_in[14]; const float* eu_b = (const float*)d_in[15];
    const float* pm_W = (const float*)d_in[16]; const float* pm_b = (const float*)d_in[17];
    const float* pu_W = (const float*)d_in[18]; const float* pu_b = (const float*)d_in[19];

    char* ws = (char*)d_ws;
    bf16* hp     = (bf16*)(ws + OFF_HP);
    float* hsum  = (float*)(ws + OFF_HSUM);
    float* psum  = (float*)(ws + OFF_PSUM);
    float* esum  = (float*)(ws + OFF_ESUM);
    float* eaggA = (float*)(ws + OFF_EAGGA);
    float* eaggB = (float*)(ws + OFF_EAGGB);
    bf16* wf     = (bf16*)(ws + OFF_WFMT);
    int* rowptr  = (int*)(ws + OFF_ROWPTR);
    int* colidx  = (int*)(ws + OFF_COLIDX);
    int* ssend   = (int*)(ws + OFF_SSEND);
    int* segarr  = (int*)(ws + OFF_SEG);
    int* cnt     = (int*)(ws + OFF_CNT);
    int* bsum    = (int*)(ws + OFF_BSUM);
    float* dout  = (float*)d_out;

    const int EB   = NE / 256;          // 3125
    const int NB64 = (NN + 63) / 64;    // 782

    // CSR build; cnt ends as deg
    (void)hipMemsetAsync(cnt, 0, NN * sizeof(int), stream);
    hist_k<<<EB, 256, 0, stream>>>(rec, cnt);
    scan1_k<<<SCAN_B, 256, 0, stream>>>(cnt, bsum);
    scan2_k<<<1, 256, 0, stream>>>(bsum);
    scan3_k<<<SCAN_B, 256, 0, stream>>>(cnt, bsum, rowptr);
    (void)hipMemsetAsync(cnt, 0, NN * sizeof(int), stream);
    scatter_k<<<EB, 256, 0, stream>>>(rec, rowptr, cnt, colidx);
    fillseg_k<<<EB, 256, 0, stream>>>(rowptr, colidx, send, segarr, ssend);

    wfmt_k<<<39, 256, 0, stream>>>(he_W, ee_W, pe_W, hm_W, hu_W, eu_W, pm_W, pu_W, wf);

    // zero hsum + psum + esum (contiguous; zero-fuse maintains hsum/psum per layer)
    (void)hipMemsetAsync(hsum, 0, (long)NN*(64 + 64 + 16)*sizeof(float), stream);

    // embeddings + bootstrap aggregates
    hemb_k<<<NB64, 256, 0, stream>>>(h_in, wf + FW_HE, he_b, hp);
    pemb_k<<<NB64, 256, 0, stream>>>(p_in, wf + FW_PE, pe_b, hp);
    esum_k<<<EB, 256, 0, stream>>>(e_in, colidx, segarr, esum);
    eembn_k<<<NB64, 256, 0, stream>>>(esum, cnt, wf + FW_EE, ee_b, eaggA);
    gsum64_k<<<EB, 256, 0, stream>>>(hp, 0,  ssend, segarr, hsum);
    gsum64_k<<<EB, 256, 0, stream>>>(hp, 64, ssend, segarr, psum);

    float* eA = eaggA;
    float* eB = eaggB;
    for (int i = 0; i < 4; ++i) {
        long base = FW_L0 + (long)i*LSTR;
        // h update (consumes hsum_i, psum_i, eagg_i; zeroes hsum)
        hfuse_k<<<NB64, 256, 0, stream>>>(hp, hsum, psum, eA, cnt,
            wf + base + R_HAGG, wf + base + R_HMR, hm_b + i*64,
            wf + base + R_HU, hu_b + i*64,
            (i == 3) ? dout : nullptr);
        // hsum_{i+1} = segsum(h_new[send])
        gsum64_k<<<EB, 256, 0, stream>>>(hp, 0, ssend, segarr, hsum);
        // p update (computes eagg_{i+1} -> eB; consumes psum_i; zeroes psum)
        pfuse_k<<<NB64, 256, 0, stream>>>(hp, hsum, psum, eA, eB, cnt,
            wf + base + R_EUS, wf + base + R_EUR, wf + base + R_EUE, eu_b + i*64,
            wf + base + R_PAGG, wf + base + R_PMR, pm_b + i*64,
            wf + base + R_PU, pu_b + i*64,
            (i == 3) ? dout + (long)NN*64 : nullptr);
        // psum_{i+1} = segsum(p_new[send])
        if (i < 3)
            gsum64_k<<<EB, 256, 0, stream>>>(hp, 64, ssend, segarr, psum);
        float* tmp = eA; eA = eB; eB = tmp;
    }
}